// Round 9
// baseline (233.791 us; speedup 1.0000x reference)
//
#include <hip/hip_runtime.h>

#define CAND_CAP 448
#define TMP_CAP 32
#define M_MAX 1024
#define FTMP_CAP 128

typedef __attribute__((ext_vector_type(8))) short bf16x8;
typedef __attribute__((ext_vector_type(4))) float f32x4;

__device__ __forceinline__ unsigned short f2bf(float x) {
  unsigned u = __float_as_uint(x);
  unsigned r = (u + 0x7fffu + ((u >> 16) & 1u)) >> 16;
  return (unsigned short)r;
}

__device__ __forceinline__ int cell_of(float x, float y, float z) {
  int cx = min((int)(x * 10.0f), 9);
  int cy = min((int)(y * 10.0f), 9);
  int cz = min((int)(z * 10.0f), 9);
  return cz * 100 + cy * 10 + cx;
}

// ============================ fused prep kernel ============================
// blocks 0..2  : per-set grid build (count -> LDS scan -> scatter), one block/set
// blocks 3..226: W2 -> MFMA B-fragment conversion
//   W2F chunk t = ((s*16+nb)*8+kt)*64+lane (8 ushorts/chunk):
//   lane l supplies B[k=kt*32+(l>>4)*8+j][n=nb*16+(l&15)], j=0..7
__global__ __launch_bounds__(256) void prep_kernel(
    const float* __restrict__ g, const float* __restrict__ s, const float* __restrict__ v,
    const float* __restrict__ W2, unsigned short* __restrict__ W2F,
    int* __restrict__ starts, float4* __restrict__ binned) {
  const int b = blockIdx.x;
  if (b < 3) {
    __shared__ int hist[1024];
    __shared__ int wsum[4];
    const int tid = threadIdx.x, lane = tid & 63, wv = tid >> 6;
    const float* p = (b == 0) ? g : (b == 1) ? s : v;
    const int Np = (b == 2) ? 8192 : 4096;
    const int base = (b == 0) ? 0 : (b == 1) ? 4096 : 8192;

    for (int i = tid; i < 1024; i += 256) hist[i] = 0;
    __syncthreads();
    for (int i = tid; i < Np; i += 256) {
      float x = p[i * 3 + 0], y = p[i * 3 + 1], z = p[i * 3 + 2];
      atomicAdd(&hist[cell_of(x, y, z)], 1);
    }
    __syncthreads();
    // exclusive scan of 1024 bins (thread owns 4 consecutive bins)
    int h0 = hist[tid * 4 + 0], h1 = hist[tid * 4 + 1];
    int h2 = hist[tid * 4 + 2], h3 = hist[tid * 4 + 3];
    int c1 = h0 + h1, c2 = c1 + h2, c3 = c2 + h3;
    int is = c3;
#pragma unroll
    for (int o = 1; o < 64; o <<= 1) {
      int t = __shfl_up(is, o, 64);
      if (lane >= o) is += t;
    }
    if (lane == 63) wsum[wv] = is;
    __syncthreads();
    int off = is - c3;
    for (int w = 0; w < wv; ++w) off += wsum[w];
    __syncthreads();                       // all hist reads done before overwrite
    hist[tid * 4 + 0] = off;               // becomes cursor
    hist[tid * 4 + 1] = off + h0;
    hist[tid * 4 + 2] = off + c1;
    hist[tid * 4 + 3] = off + c2;
    starts[b * 1024 + tid * 4 + 0] = off;  // bin 1000 gets the total (bins>=1000 empty)
    starts[b * 1024 + tid * 4 + 1] = off + h0;
    starts[b * 1024 + tid * 4 + 2] = off + c1;
    starts[b * 1024 + tid * 4 + 3] = off + c2;
    __syncthreads();
    for (int i = tid; i < Np; i += 256) {
      float x = p[i * 3 + 0], y = p[i * 3 + 1], z = p[i * 3 + 2];
      int pos = atomicAdd(&hist[cell_of(x, y, z)], 1);
      binned[base + pos] = make_float4(x, y, z, __int_as_float(i));
    }
  } else {
    int t = (b - 3) * 256 + threadIdx.x;   // 0..57343
    int s_ = t >> 13;
    int rem = t & 8191;
    int nb = rem >> 9;
    int rem2 = rem & 511;
    int kt = rem2 >> 6;
    int l = rem2 & 63;
    int n = nb * 16 + (l & 15);
    int k0 = kt * 32 + (l >> 4) * 8;
    bf16x8 vfr;
#pragma unroll
    for (int j = 0; j < 8; ++j)
      vfr[j] = (short)f2bf(W2[((size_t)s_ * 256 + (k0 + j)) * 256 + n]);
    *(bf16x8*)(W2F + (size_t)t * 8) = vfr;
  }
}

// ============================ merged select kernel ============================
struct SelDesc {
  const float* qptr[7];
  const float* pptr[7];
  int pbase[7];
  int soff[7];
  int w1off[7];
  int b1off[7];
  int foff[7];
  int blkstart[8];
};

__global__ __launch_bounds__(256) void bq_select_grid(
    SelDesc d, const float* __restrict__ W1all, const float* __restrict__ b1all,
    const float4* __restrict__ binned, const int* __restrict__ starts,
    unsigned short* __restrict__ fbuf) {
  __shared__ unsigned long long keys[4][CAND_CAP];
  __shared__ unsigned long long tmpb[4][2][TMP_CAP];
  __shared__ unsigned long long Tkey[4][2];
  __shared__ int hist32[4][256];
  __shared__ int bbin[4][2];
  __shared__ int msel[4][2];
  __shared__ float4 sel[4][32];
  __shared__ int rowstart[4][28];
  __shared__ int rowadj[4][28];

  const int tid = threadIdx.x, lane = tid & 63, wv = tid >> 6;

  int st = 0;
  while ((int)blockIdx.x >= d.blkstart[st + 1]) ++st;
  const int qlocal = ((int)blockIdx.x - d.blkstart[st]) * 4 + wv;
  const float* qpts = d.qptr[st];
  const float* ppts = d.pptr[st];
  const int pbase = d.pbase[st];
  const int soff = d.soff[st];

#pragma unroll
  for (int i = 0; i < 4; ++i) hist32[wv][lane + 64 * i] = 0;
  if (lane == 0) {
    Tkey[wv][0] = 0; Tkey[wv][1] = 0;
    bbin[wv][0] = -1; bbin[wv][1] = -1;
    msel[wv][0] = 0; msel[wv][1] = 0;
  }
  const float qx = qpts[qlocal * 3 + 0];
  const float qy = qpts[qlocal * 3 + 1];
  const float qz = qpts[qlocal * 3 + 2];

  // ---- flattened row table with per-row x-chord culling ----
  const int cy0 = max(0, (int)floorf((qy - 0.2f) * 10.0f));
  const int cy1 = min(9, (int)floorf((qy + 0.2f) * 10.0f));
  const int cz0 = max(0, (int)floorf((qz - 0.2f) * 10.0f));
  const int cz1 = min(9, (int)floorf((qz + 0.2f) * 10.0f));
  const int ncy = cy1 - cy0 + 1;
  const int nrows = (cz1 - cz0 + 1) * ncy;

  int len = 0, beg = 0;
  if (lane < nrows) {
    int czi = lane / ncy;
    int cz = cz0 + czi;
    int cy = cy0 + (lane - czi * ncy);
    float lo = cz * 0.1f;
    float dz = fmaxf(fmaxf(lo - qz, qz - (lo + 0.1f)), 0.0f);
    float loy = cy * 0.1f;
    float dy = fmaxf(fmaxf(loy - qy, qy - (loy + 0.1f)), 0.0f);
    float dyz2 = dz * dz + dy * dy;
    if (dyz2 <= 0.04f) {
      float xr = __builtin_sqrtf(0.04f - dyz2);
      int cxlo = max(0, (int)floorf((qx - xr) * 10.0f));
      int cxhi = min(9, (int)floorf((qx + xr) * 10.0f));
      int row = cz * 100 + cy * 10;
      beg = starts[soff + row + cxlo];
      int end = starts[soff + row + cxhi + 1];
      len = end - beg;
    }
  }
  int incl = len;
#pragma unroll
  for (int o = 1; o < 64; o <<= 1) {
    int t = __shfl_up(incl, o, 64);
    if (lane >= o) incl += t;
  }
  const int T = __shfl(incl, 63, 64);
  int excl = incl - len;
  if (lane <= nrows) { rowstart[wv][lane] = excl; rowadj[wv][lane] = beg - excl; }
  __builtin_amdgcn_wave_barrier();
  __threadfence_block();

  // ---- dense scan, ballot compaction, ballot c16 count ----
  int cnt = 0, c16 = 0;
  {
    int r = 0;
    for (int jb = 0; jb < T; jb += 64) {
      int j = jb + lane;
      bool in = j < T;
      float d2 = 1e30f;
      unsigned orig = 0;
      if (in) {
        while (j >= rowstart[wv][r + 1]) ++r;
        int idx = j + rowadj[wv][r];
        float4 P = binned[pbase + idx];
        float dx = P.x - qx, dy = P.y - qy, dz = P.z - qz;
        d2 = dx * dx + dy * dy + dz * dz;
        orig = (unsigned)__float_as_int(P.w);
      }
      bool pred = in && (d2 <= 0.04f);
      unsigned long long mask = __ballot(pred);
      if (pred) {
        int mypos = cnt + __popcll(mask & ((1ull << lane) - 1ull));
        if (mypos < CAND_CAP)
          keys[wv][mypos] = ((unsigned long long)__float_as_uint(d2) << 32) | orig;
        int b = min((int)(d2 * 6400.0f), 255);
        atomicAdd(&hist32[wv][b], 1);
      }
      cnt += __popcll(mask);
      c16 += __popcll(__ballot(d2 <= 0.01f));
    }
  }
  __builtin_amdgcn_wave_barrier();
  __threadfence_block();
  const int cntf = min(cnt, CAND_CAP);
  const int k32 = min(32, cntf);
  const int k16 = min(16, c16);

  // ---- hist32 prefix scan; boundary bins for BOTH k32 and k16 ----
  {
    int h0 = hist32[wv][lane * 4 + 0];
    int h1 = hist32[wv][lane * 4 + 1];
    int h2 = hist32[wv][lane * 4 + 2];
    int h3 = hist32[wv][lane * 4 + 3];
    int c1 = h0 + h1, c2 = c1 + h2, c3 = c2 + h3;
    int is = c3;
#pragma unroll
    for (int o = 1; o < 64; o <<= 1) {
      int t = __shfl_up(is, o, 64);
      if (lane >= o) is += t;
    }
    int off = is - c3;
    int cum0 = off + h0, cum1 = off + c1, cum2 = off + c2, cum3 = off + c3;
    if (k32 > 0) {
      if (cum0 >= k32 && off  < k32) { bbin[wv][1] = lane * 4 + 0; msel[wv][1] = k32 - off;  }
      if (cum1 >= k32 && cum0 < k32) { bbin[wv][1] = lane * 4 + 1; msel[wv][1] = k32 - cum0; }
      if (cum2 >= k32 && cum1 < k32) { bbin[wv][1] = lane * 4 + 2; msel[wv][1] = k32 - cum1; }
      if (cum3 >= k32 && cum2 < k32) { bbin[wv][1] = lane * 4 + 3; msel[wv][1] = k32 - cum2; }
    }
    if (k16 > 0) {
      if (cum0 >= k16 && off  < k16) { bbin[wv][0] = lane * 4 + 0; msel[wv][0] = k16 - off;  }
      if (cum1 >= k16 && cum0 < k16) { bbin[wv][0] = lane * 4 + 1; msel[wv][0] = k16 - cum0; }
      if (cum2 >= k16 && cum1 < k16) { bbin[wv][0] = lane * 4 + 2; msel[wv][0] = k16 - cum1; }
      if (cum3 >= k16 && cum2 < k16) { bbin[wv][0] = lane * 4 + 3; msel[wv][0] = k16 - cum2; }
    }
  }
  __builtin_amdgcn_wave_barrier();
  __threadfence_block();
  const int b32b = bbin[wv][1];
  const int b16b = bbin[wv][0];

  // ---- collect boundary-bin keys (ballot compaction, both scales) ----
  int t32c = 0, t16c = 0;
  for (int base = 0; base < cntf; base += 64) {
    int i = base + lane;
    bool in = i < cntf;
    unsigned long long key = in ? keys[wv][i] : 0xFFFFFFFFFFFFFFFFull;
    float d2 = __uint_as_float((unsigned)(key >> 32));
    int b = min((int)(d2 * 6400.0f), 255);
    bool p1 = in && (b == b32b);
    unsigned long long m1 = __ballot(p1);
    if (p1) {
      int pos = t32c + __popcll(m1 & ((1ull << lane) - 1ull));
      if (pos < TMP_CAP) tmpb[wv][1][pos] = key;
    }
    t32c += __popcll(m1);
    bool p0 = in && (b == b16b);
    unsigned long long m0 = __ballot(p0);
    if (p0) {
      int pos = t16c + __popcll(m0 & ((1ull << lane) - 1ull));
      if (pos < TMP_CAP) tmpb[wv][0][pos] = key;
    }
    t16c += __popcll(m0);
  }
  __builtin_amdgcn_wave_barrier();
  __threadfence_block();

  // ---- rank-select m-th smallest key in each boundary bin ----
#pragma unroll
  for (int s = 0; s < 2; ++s) {
    const int k = s ? k32 : k16;
    if (k > 0) {
      const int h = min(s ? t32c : t16c, TMP_CAP);
      const int m = msel[wv][s];
      if (lane < h) {
        unsigned long long e = tmpb[wv][s][lane];
        int less = 0;
        for (int j = 0; j < h; ++j) less += (tmpb[wv][s][j] < e) ? 1 : 0;
        if (less == m - 1) Tkey[wv][s] = e;
      }
    }
  }
  __builtin_amdgcn_wave_barrier();
  __threadfence_block();
  const unsigned long long T32 = Tkey[wv][1];
  const unsigned long long T16 = Tkey[wv][0];

  // ---- compact selected neighbors (ballot), rel from raw points ----
  int sc = 0;
  for (int base = 0; base < cntf; base += 64) {
    int i = base + lane;
    bool in = i < cntf;
    unsigned long long key = in ? keys[wv][i] : 0xFFFFFFFFFFFFFFFFull;
    bool pred = in && (k32 > 0) && (key <= T32);
    unsigned long long mask = __ballot(pred);
    if (pred) {
      int pos = sc + __popcll(mask & ((1ull << lane) - 1ull));
      if (pos < 32) {
        int idx = (int)(key & 0xffffffffu);
        float rx = ppts[idx * 3 + 0] - qx;
        float ry = ppts[idx * 3 + 1] - qy;
        float rz = ppts[idx * 3 + 2] - qz;
        bool f16 = (k16 > 0) && (key <= T16);
        sel[wv][pos] = make_float4(rx, ry, rz, f16 ? 1.0f : 0.0f);
      }
    }
    sc += __popcll(mask);
  }
  __builtin_amdgcn_wave_barrier();
  __threadfence_block();
  const int nsel = min(sc, 32);

  // ---- masked max-pool -> bf16 fbuf row ----
  {
    const float* W1 = W1all + d.w1off[st];
    const float* b1 = b1all + d.b1off[st];
    const int scale = lane >> 5;
    const int hbase = (lane & 31) * 4;
    const float4 wx = *(const float4*)(W1 + scale * 384 + 0 * 128 + hbase);
    const float4 wy = *(const float4*)(W1 + scale * 384 + 1 * 128 + hbase);
    const float4 wz = *(const float4*)(W1 + scale * 384 + 2 * 128 + hbase);
    const float4 bb = *(const float4*)(b1 + scale * 128 + hbase);
    float m0 = -INFINITY, m1 = -INFINITY, m2 = -INFINITY, m3 = -INFINITY;
    for (int n = 0; n < nsel; ++n) {
      float4 e = sel[wv][n];
      bool ok = scale ? true : (e.w > 0.5f);
      float v0 = e.x * wx.x + e.y * wy.x + e.z * wz.x;
      float v1 = e.x * wx.y + e.y * wy.y + e.z * wz.y;
      float v2 = e.x * wx.z + e.y * wy.z + e.z * wz.z;
      float v3 = e.x * wx.w + e.y * wy.w + e.z * wz.w;
      if (ok) { m0 = fmaxf(m0, v0); m1 = fmaxf(m1, v1); m2 = fmaxf(m2, v2); m3 = fmaxf(m3, v3); }
    }
    ushort4 o;
    o.x = f2bf(fmaxf(m0 + bb.x, 0.0f));
    o.y = f2bf(fmaxf(m1 + bb.y, 0.0f));
    o.z = f2bf(fmaxf(m2 + bb.z, 0.0f));
    o.w = f2bf(fmaxf(m3 + bb.w, 0.0f));
    *(ushort4*)(fbuf + (size_t)(d.foff[st] + qlocal) * 256 + lane * 4) = o;
  }
}

// ============================ MFMA GEMM kernel ============================
struct GemmDesc {
  const float* basep[3];
  float* outp[3];
  int blkstart[4];
  int nst[3];
  int foff[3][3];
  int w2off[3][3];
  int b2off[3][3];
};

__global__ __launch_bounds__(256) void bq_gemm_mfma(
    GemmDesc d, const unsigned short* __restrict__ W2F,
    const float* __restrict__ b2all, const unsigned short* __restrict__ fbuf) {
  __shared__ unsigned short ftile[32][264];
  const int tid = threadIdx.x, lane = tid & 63, wv = tid >> 6;

  int rg = 0;
  while ((int)blockIdx.x >= d.blkstart[rg + 1]) ++rg;
  const int qb = ((int)blockIdx.x - d.blkstart[rg]) * 32;

  f32x4 acc[2][4];
#pragma unroll
  for (int mt = 0; mt < 2; ++mt)
#pragma unroll
    for (int nt = 0; nt < 4; ++nt) acc[mt][nt] = (f32x4)0.0f;

  const int nst = d.nst[rg];
  for (int s = 0; s < nst; ++s) {
    __syncthreads();
    {
      const unsigned short* fsrc = fbuf + (size_t)(d.foff[rg][s] + qb) * 256;
#pragma unroll
      for (int i = 0; i < 4; ++i) {
        int c = tid + 256 * i;
        int row = c >> 5, k8 = (c & 31) * 8;
        *(uint4*)&ftile[row][k8] = *(const uint4*)(fsrc + (size_t)row * 256 + k8);
      }
    }
    __syncthreads();
    const unsigned short* wbase = W2F + d.w2off[rg][s];
#pragma unroll
    for (int kt = 0; kt < 8; ++kt) {
      const int koff = kt * 32 + (lane >> 4) * 8;
      bf16x8 a0 = *(const bf16x8*)&ftile[lane & 15][koff];
      bf16x8 a1 = *(const bf16x8*)&ftile[16 + (lane & 15)][koff];
#pragma unroll
      for (int nt = 0; nt < 4; ++nt) {
        int nb = wv * 4 + nt;
        bf16x8 bfr = *(const bf16x8*)(wbase + (size_t)((nb * 8 + kt) * 64 + lane) * 8);
        acc[0][nt] = __builtin_amdgcn_mfma_f32_16x16x32_bf16(a0, bfr, acc[0][nt], 0, 0, 0);
        acc[1][nt] = __builtin_amdgcn_mfma_f32_16x16x32_bf16(a1, bfr, acc[1][nt], 0, 0, 0);
      }
    }
  }

  float bb[4];
#pragma unroll
  for (int nt = 0; nt < 4; ++nt) {
    int c = wv * 64 + nt * 16 + (lane & 15);
    float sum = 0.0f;
    for (int s = 0; s < nst; ++s) sum += b2all[d.b2off[rg][s] + c];
    bb[nt] = sum;
  }

  const float* __restrict__ basep = d.basep[rg];
  float* __restrict__ outp = d.outp[rg];
#pragma unroll
  for (int mt = 0; mt < 2; ++mt) {
#pragma unroll
    for (int r = 0; r < 4; ++r) {
      int q = qb + mt * 16 + (lane >> 4) * 4 + r;
#pragma unroll
      for (int nt = 0; nt < 4; ++nt) {
        int c = wv * 64 + nt * 16 + (lane & 15);
        outp[(size_t)q * 256 + c] = basep[(size_t)q * 256 + c] + acc[mt][nt][r] + bb[nt];
      }
    }
  }
}

// ============================ fused fallback (tiny ws) ============================
__global__ __launch_bounds__(256) void init_out_kernel(
    const float* __restrict__ g, const float* __restrict__ s, const float* __restrict__ v,
    float* __restrict__ out) {
  const int NG = 4096 * 256, NS = 4096 * 256;
  int i = blockIdx.x * 256 + threadIdx.x;
  if (i < NG) out[i] = g[i];
  else if (i < NG + NS) out[i] = s[i - NG];
  else out[i] = v[i - NG - NS];
}

__global__ __launch_bounds__(256) void bq_stack_fused(
    const float* __restrict__ qpts,
    const float* __restrict__ ppts, int Np,
    const float* __restrict__ W1, const float* __restrict__ b1,
    const float* __restrict__ W2, const float* __restrict__ b2,
    float* __restrict__ out) {
  __shared__ unsigned long long keys[M_MAX];
  __shared__ int hist32[256];
  __shared__ int hist16[64];
  __shared__ unsigned long long tmpb[2][FTMP_CAP];
  __shared__ int tmpcnt[2];
  __shared__ float4 sel[32];
  __shared__ int selcnt;
  __shared__ float f_lds[256];
  __shared__ int cnt_s;
  __shared__ unsigned long long T_lds[2];
  __shared__ int bbin[2], msel[2];
  __shared__ int wsum[4];
  __shared__ float qsh[3];

  const int tid = threadIdx.x;
  const int lane = tid & 63;
  const int wv = tid >> 6;
  const int q = blockIdx.x;

  hist32[tid] = 0;
  if (tid < 64) hist16[tid] = 0;
  if (tid == 0) {
    cnt_s = 0; selcnt = 0; tmpcnt[0] = 0; tmpcnt[1] = 0;
    T_lds[0] = ~0ULL; T_lds[1] = ~0ULL;
    qsh[0] = qpts[q * 3 + 0]; qsh[1] = qpts[q * 3 + 1]; qsh[2] = qpts[q * 3 + 2];
  }
  __syncthreads();
  const float qx = qsh[0], qy = qsh[1], qz = qsh[2];

  const float4* pp4 = (const float4*)ppts;
  const int groups = Np >> 2;
  for (int gp = tid; gp < groups; gp += 256) {
    float4 A = pp4[gp * 3 + 0];
    float4 Bv = pp4[gp * 3 + 1];
    float4 C = pp4[gp * 3 + 2];
    float px[4] = {A.x, A.w, Bv.z, C.y};
    float py[4] = {A.y, Bv.x, Bv.w, C.z};
    float pz[4] = {A.z, Bv.y, C.x, C.w};
#pragma unroll
    for (int t = 0; t < 4; ++t) {
      float dx = px[t] - qx, dy = py[t] - qy, dz = pz[t] - qz;
      float d2 = dx * dx + dy * dy + dz * dz;
      if (d2 <= 0.04f) {
        int pos = atomicAdd(&cnt_s, 1);
        if (pos < M_MAX)
          keys[pos] = ((unsigned long long)__float_as_uint(d2) << 32) | (unsigned)(gp * 4 + t);
        int b = min((int)(d2 * 6400.0f), 255);
        atomicAdd(&hist32[b], 1);
        if (d2 <= 0.01f) atomicAdd(&hist16[min(b, 63)], 1);
      }
    }
  }
  __syncthreads();
  const int cnt = min(cnt_s, M_MAX);

  {
    int v = hist32[tid];
#pragma unroll
    for (int o = 1; o < 64; o <<= 1) {
      int t = __shfl_up(v, o, 64);
      if (lane >= o) v += t;
    }
    if (lane == 63) wsum[wv] = v;
    int v16 = 0;
    if (wv == 0) {
      v16 = hist16[lane];
#pragma unroll
      for (int o = 1; o < 64; o <<= 1) {
        int t = __shfl_up(v16, o, 64);
        if (lane >= o) v16 += t;
      }
    }
    __syncthreads();
    int off = 0;
    for (int w = 0; w < wv; ++w) off += wsum[w];
    hist32[tid] = v + off;
    if (wv == 0) hist16[lane] = v16;
    __syncthreads();
  }

  const int k32 = min(32, cnt);
  const int c16tot = hist16[63];
  const int k16 = min(16, c16tot);

  {
    int c = hist32[tid], cp = tid ? hist32[tid - 1] : 0;
    if (k32 > 0 && c >= k32 && cp < k32) { bbin[1] = tid; msel[1] = k32 - cp; }
    if (tid < 64) {
      int c6 = hist16[tid], cp6 = tid ? hist16[tid - 1] : 0;
      if (k16 > 0 && c6 >= k16 && cp6 < k16) { bbin[0] = tid; msel[0] = k16 - cp6; }
    }
  }
  __syncthreads();

  const int b32b = (k32 > 0) ? bbin[1] : -1;
  const int b16b = (k16 > 0) ? bbin[0] : -1;
  for (int i = tid; i < cnt; i += 256) {
    unsigned long long key = keys[i];
    float d2 = __uint_as_float((unsigned)(key >> 32));
    int b = min((int)(d2 * 6400.0f), 255);
    if (b == b32b) { int p = atomicAdd(&tmpcnt[1], 1); if (p < FTMP_CAP) tmpb[1][p] = key; }
    if (d2 <= 0.01f && min(b, 63) == b16b) {
      int p = atomicAdd(&tmpcnt[0], 1); if (p < FTMP_CAP) tmpb[0][p] = key;
    }
  }
  __syncthreads();

  if (wv < 2) {
    const int s = 1 - wv;
    const int k = s ? k32 : k16;
    if (k > 0) {
      const int h = min(tmpcnt[s], FTMP_CAP);
      const int m = msel[s];
      for (int base = 0; base < h; base += 64) {
        int ii = base + lane;
        if (ii < h) {
          unsigned long long e = tmpb[s][ii];
          int less = 0;
          for (int j = 0; j < h; ++j) less += (tmpb[s][j] < e) ? 1 : 0;
          if (less == m - 1) T_lds[s] = e;
        }
      }
    }
  }
  __syncthreads();

  {
    const unsigned long long T32 = (k32 > 0) ? T_lds[1] : 0ULL;
    const unsigned long long T16 = T_lds[0];
    for (int i = tid; i < cnt; i += 256) {
      unsigned long long key = keys[i];
      if (k32 > 0 && key <= T32) {
        float d2 = __uint_as_float((unsigned)(key >> 32));
        int idx = (int)(key & 0xffffffffu);
        float rx = ppts[idx * 3 + 0] - qx;
        float ry = ppts[idx * 3 + 1] - qy;
        float rz = ppts[idx * 3 + 2] - qz;
        bool f16 = (k16 > 0) && (d2 <= 0.01f) && (key <= T16);
        int slot = atomicAdd(&selcnt, 1);
        if (slot < 32) sel[slot] = make_float4(rx, ry, rz, f16 ? 1.0f : 0.0f);
      }
    }
  }
  __syncthreads();

  {
    const int nsel = min(selcnt, 32);
    const int scale = tid >> 7;
    const int h = tid & 127;
    const float w0 = W1[(scale * 3 + 0) * 128 + h];
    const float w1 = W1[(scale * 3 + 1) * 128 + h];
    const float w2 = W1[(scale * 3 + 2) * 128 + h];
    const float bb = b1[scale * 128 + h];
    float maxv = -INFINITY;
    for (int j = 0; j < nsel; ++j) {
      float4 e = sel[j];
      float val = e.x * w0 + e.y * w1 + e.z * w2;
      bool ok = scale ? true : (e.w > 0.5f);
      maxv = ok ? fmaxf(maxv, val) : maxv;
    }
    f_lds[tid] = fmaxf(maxv + bb, 0.0f);
  }
  __syncthreads();

  float* part = (float*)keys;
  {
    float4 acc = make_float4(0.f, 0.f, 0.f, 0.f);
    for (int r = 0; r < 64; ++r) {
      float fv = f_lds[wv * 64 + r];
      float4 w = ((const float4*)W2)[(wv * 64 + r) * 64 + lane];
      acc.x += fv * w.x; acc.y += fv * w.y; acc.z += fv * w.z; acc.w += fv * w.w;
    }
    ((float4*)part)[wv * 64 + lane] = acc;
  }
  __syncthreads();
  {
    float sum = part[0 * 256 + tid] + part[1 * 256 + tid] + part[2 * 256 + tid] +
                part[3 * 256 + tid] + b2[tid];
    out[q * 256 + tid] += sum;
  }
}

// ============================ launch ============================
extern "C" void kernel_launch(void* const* d_in, const int* in_sizes, int n_in,
                              void* d_out, int out_size, void* d_ws, size_t ws_size,
                              hipStream_t stream) {
  const float* g      = (const float*)d_in[0];
  const float* s      = (const float*)d_in[1];
  const float* v      = (const float*)d_in[2];
  const float* geo_t  = (const float*)d_in[3];
  const float* surf_t = (const float*)d_in[4];
  const float* vol_t  = (const float*)d_in[5];
  const float* W1     = (const float*)d_in[6];
  const float* b1     = (const float*)d_in[7];
  const float* W2     = (const float*)d_in[8];
  const float* b2     = (const float*)d_in[9];
  float* out = (float*)d_out;

  const int NG = 4096, NS = 4096, NV = 8192;
  float* out_g = out;
  float* out_s = out + NG * 256;
  float* out_v = out + (NG + NS) * 256;

  const int stackid[7] = {0, 3, 4, 1, 5, 2, 6};
  const float* qp[7]   = {g, g, g, s, s, v, v};
  const int    nq[7]   = {NG, NG, NG, NS, NS, NV, NV};
  const int    pset[7] = {0, 1, 2, 1, 0, 2, 0};
  const float* praw[3] = {g, s, v};
  const int    setbase[3] = {0, 4096, 8192};

  const size_t FB = (size_t)36864 * 256 * sizeof(unsigned short);  // bf16 fbuf
  const size_t WT = (size_t)7 * 256 * 256 * sizeof(unsigned short);
  const size_t GI = (size_t)3 * 1024 * sizeof(int);
  const size_t need = FB + WT + GI + (size_t)16384 * sizeof(float4);

  if (ws_size >= need) {
    unsigned short* fbuf = (unsigned short*)d_ws;
    unsigned short* W2F  = (unsigned short*)((char*)d_ws + FB);
    int* starts = (int*)((char*)d_ws + FB + WT);
    float4* binned = (float4*)((char*)d_ws + FB + WT + GI);

    // node 1: fused prep (grid build x3 blocks + W2 fragment convert x224 blocks)
    hipLaunchKernelGGL(prep_kernel, dim3(227), dim3(256), 0, stream,
                       g, s, v, W2, W2F, starts, binned);

    // node 2: merged select
    SelDesc sd;
    int blk = 0, frow = 0;
    int foffs[7];
    for (int i = 0; i < 7; ++i) {
      sd.qptr[i] = qp[i];
      sd.pptr[i] = praw[pset[i]];
      sd.pbase[i] = setbase[pset[i]];
      sd.soff[i] = pset[i] * 1024;
      sd.w1off[i] = stackid[i] * 768;
      sd.b1off[i] = stackid[i] * 256;
      sd.foff[i] = frow;
      foffs[i] = frow;
      sd.blkstart[i] = blk;
      blk += nq[i] / 4;
      frow += nq[i];
    }
    sd.blkstart[7] = blk;
    hipLaunchKernelGGL(bq_select_grid, dim3(blk), dim3(256), 0, stream,
                       sd, W1, b1, binned, starts, fbuf);

    // node 3: merged MFMA GEMM
    GemmDesc gd;
    gd.basep[0] = geo_t;  gd.outp[0] = out_g;
    gd.basep[1] = surf_t; gd.outp[1] = out_s;
    gd.basep[2] = vol_t;  gd.outp[2] = out_v;
    gd.blkstart[0] = 0;
    gd.blkstart[1] = NG / 32;
    gd.blkstart[2] = NG / 32 + NS / 32;
    gd.blkstart[3] = NG / 32 + NS / 32 + NV / 32;
    gd.nst[0] = 3; gd.nst[1] = 2; gd.nst[2] = 2;
    const int ridx[3][3] = {{0, 1, 2}, {3, 4, -1}, {5, 6, -1}};
    for (int r = 0; r < 3; ++r)
      for (int t = 0; t < gd.nst[r]; ++t) {
        int i = ridx[r][t];
        gd.foff[r][t] = foffs[i];
        gd.w2off[r][t] = stackid[i] * 256 * 256;
        gd.b2off[r][t] = stackid[i] * 256;
      }
    hipLaunchKernelGGL(bq_gemm_mfma, dim3(gd.blkstart[3]), dim3(256), 0, stream,
                       gd, W2F, b2, fbuf);
  } else {
    const int total = (NG + NS + NV) * 256;
    hipLaunchKernelGGL(init_out_kernel, dim3(total / 256), dim3(256), 0, stream,
                       geo_t, surf_t, vol_t, out);
    auto launch = [&](int stack, const float* qp_, int Nq, const float* pp_, int Np, float* o) {
      hipLaunchKernelGGL(bq_stack_fused, dim3(Nq), dim3(256), 0, stream,
                         qp_, pp_, Np, W1 + stack * 768, b1 + stack * 256,
                         W2 + stack * 256 * 256, b2 + stack * 256, o);
    };
    launch(0, g, NG, g, NG, out_g);
    launch(3, g, NG, s, NS, out_g);
    launch(4, g, NG, v, NV, out_g);
    launch(1, s, NS, s, NS, out_s);
    launch(5, s, NS, g, NG, out_s);
    launch(2, v, NV, v, NV, out_v);
    launch(6, v, NV, g, NG, out_v);
  }
}

// Round 10
// 224.605 us; speedup vs baseline: 1.0409x; 1.0409x over previous
//
#include <hip/hip_runtime.h>

#define CAND_CAP 448
#define TMP_CAP 32
#define M_MAX 1024
#define FTMP_CAP 128

typedef __attribute__((ext_vector_type(8))) short bf16x8;
typedef __attribute__((ext_vector_type(4))) float f32x4;
typedef __attribute__((ext_vector_type(2))) float f32x2;

__device__ __forceinline__ unsigned short f2bf(float x) {
  unsigned u = __float_as_uint(x);
  unsigned r = (u + 0x7fffu + ((u >> 16) & 1u)) >> 16;
  return (unsigned short)r;
}

__device__ __forceinline__ int cell_of(float x, float y, float z) {
  int cx = min((int)(x * 10.0f), 9);
  int cy = min((int)(y * 10.0f), 9);
  int cz = min((int)(z * 10.0f), 9);
  return cz * 100 + cy * 10 + cx;
}

// ============================ fused prep kernel ============================
// blocks 0..2  : per-set grid build (count -> LDS scan -> scatter), one block/set
// blocks 3..226: W2 -> MFMA B-fragment conversion
__global__ __launch_bounds__(256) void prep_kernel(
    const float* __restrict__ g, const float* __restrict__ s, const float* __restrict__ v,
    const float* __restrict__ W2, unsigned short* __restrict__ W2F,
    int* __restrict__ starts, float4* __restrict__ binned) {
  const int b = blockIdx.x;
  if (b < 3) {
    __shared__ int hist[1024];
    __shared__ int wsum[4];
    const int tid = threadIdx.x, lane = tid & 63, wv = tid >> 6;
    const float* p = (b == 0) ? g : (b == 1) ? s : v;
    const int Np = (b == 2) ? 8192 : 4096;
    const int base = (b == 0) ? 0 : (b == 1) ? 4096 : 8192;

    for (int i = tid; i < 1024; i += 256) hist[i] = 0;
    __syncthreads();
    for (int i = tid; i < Np; i += 256) {
      float x = p[i * 3 + 0], y = p[i * 3 + 1], z = p[i * 3 + 2];
      atomicAdd(&hist[cell_of(x, y, z)], 1);
    }
    __syncthreads();
    int h0 = hist[tid * 4 + 0], h1 = hist[tid * 4 + 1];
    int h2 = hist[tid * 4 + 2], h3 = hist[tid * 4 + 3];
    int c1 = h0 + h1, c2 = c1 + h2, c3 = c2 + h3;
    int is = c3;
#pragma unroll
    for (int o = 1; o < 64; o <<= 1) {
      int t = __shfl_up(is, o, 64);
      if (lane >= o) is += t;
    }
    if (lane == 63) wsum[wv] = is;
    __syncthreads();
    int off = is - c3;
    for (int w = 0; w < wv; ++w) off += wsum[w];
    __syncthreads();
    hist[tid * 4 + 0] = off;
    hist[tid * 4 + 1] = off + h0;
    hist[tid * 4 + 2] = off + c1;
    hist[tid * 4 + 3] = off + c2;
    starts[b * 1024 + tid * 4 + 0] = off;
    starts[b * 1024 + tid * 4 + 1] = off + h0;
    starts[b * 1024 + tid * 4 + 2] = off + c1;
    starts[b * 1024 + tid * 4 + 3] = off + c2;
    __syncthreads();
    for (int i = tid; i < Np; i += 256) {
      float x = p[i * 3 + 0], y = p[i * 3 + 1], z = p[i * 3 + 2];
      int pos = atomicAdd(&hist[cell_of(x, y, z)], 1);
      binned[base + pos] = make_float4(x, y, z, __int_as_float(i));
    }
  } else {
    int t = (b - 3) * 256 + threadIdx.x;
    int s_ = t >> 13;
    int rem = t & 8191;
    int nb = rem >> 9;
    int rem2 = rem & 511;
    int kt = rem2 >> 6;
    int l = rem2 & 63;
    int n = nb * 16 + (l & 15);
    int k0 = kt * 32 + (l >> 4) * 8;
    bf16x8 vfr;
#pragma unroll
    for (int j = 0; j < 8; ++j)
      vfr[j] = (short)f2bf(W2[((size_t)s_ * 256 + (k0 + j)) * 256 + n]);
    *(bf16x8*)(W2F + (size_t)t * 8) = vfr;
  }
}

// ============================ merged select kernel ============================
struct SelDesc {
  const float* qptr[7];
  const float* pptr[7];
  int pbase[7];
  int soff[7];
  int w1off[7];
  int b1off[7];
  int foff[7];
  int blkstart[8];
};

__global__ __launch_bounds__(256) void bq_select_grid(
    SelDesc d, const float* __restrict__ W1all, const float* __restrict__ b1all,
    const float4* __restrict__ binned, const int* __restrict__ starts,
    unsigned short* __restrict__ fbuf) {
  __shared__ unsigned long long keys[4][CAND_CAP];
  __shared__ unsigned long long tmpb[4][2][TMP_CAP];
  __shared__ unsigned long long Tkey[4][2];
  __shared__ int hist32[4][256];
  __shared__ int bbin[4][2];
  __shared__ int msel[4][2];
  __shared__ float4 sel[4][32];
  __shared__ float4 sel16[4][16];
  __shared__ int rowstart[4][28];
  __shared__ int rowadj[4][28];

  const int tid = threadIdx.x, lane = tid & 63, wv = tid >> 6;

  int st = 0;
  while ((int)blockIdx.x >= d.blkstart[st + 1]) ++st;
  const int qlocal = ((int)blockIdx.x - d.blkstart[st]) * 4 + wv;
  const float* qpts = d.qptr[st];
  const float* ppts = d.pptr[st];
  const int pbase = d.pbase[st];
  const int soff = d.soff[st];

#pragma unroll
  for (int i = 0; i < 4; ++i) hist32[wv][lane + 64 * i] = 0;
  if (lane == 0) {
    Tkey[wv][0] = 0; Tkey[wv][1] = 0;
    bbin[wv][0] = -1; bbin[wv][1] = -1;
    msel[wv][0] = 0; msel[wv][1] = 0;
  }
  const float qx = qpts[qlocal * 3 + 0];
  const float qy = qpts[qlocal * 3 + 1];
  const float qz = qpts[qlocal * 3 + 2];

  // ---- flattened row table with per-row x-chord culling ----
  const int cy0 = max(0, (int)floorf((qy - 0.2f) * 10.0f));
  const int cy1 = min(9, (int)floorf((qy + 0.2f) * 10.0f));
  const int cz0 = max(0, (int)floorf((qz - 0.2f) * 10.0f));
  const int cz1 = min(9, (int)floorf((qz + 0.2f) * 10.0f));
  const int ncy = cy1 - cy0 + 1;
  const int nrows = (cz1 - cz0 + 1) * ncy;

  int len = 0, beg = 0;
  if (lane < nrows) {
    int czi = lane / ncy;
    int cz = cz0 + czi;
    int cy = cy0 + (lane - czi * ncy);
    float lo = cz * 0.1f;
    float dz = fmaxf(fmaxf(lo - qz, qz - (lo + 0.1f)), 0.0f);
    float loy = cy * 0.1f;
    float dy = fmaxf(fmaxf(loy - qy, qy - (loy + 0.1f)), 0.0f);
    float dyz2 = dz * dz + dy * dy;
    if (dyz2 <= 0.04f) {
      float xr = __builtin_sqrtf(0.04f - dyz2);
      int cxlo = max(0, (int)floorf((qx - xr) * 10.0f));
      int cxhi = min(9, (int)floorf((qx + xr) * 10.0f));
      int row = cz * 100 + cy * 10;
      beg = starts[soff + row + cxlo];
      int end = starts[soff + row + cxhi + 1];
      len = end - beg;
    }
  }
  int incl = len;
#pragma unroll
  for (int o = 1; o < 64; o <<= 1) {
    int t = __shfl_up(incl, o, 64);
    if (lane >= o) incl += t;
  }
  const int T = __shfl(incl, 63, 64);
  int excl = incl - len;
  if (lane <= nrows) { rowstart[wv][lane] = excl; rowadj[wv][lane] = beg - excl; }
  __builtin_amdgcn_wave_barrier();
  __threadfence_block();

  // ---- dense scan, ballot compaction, ballot c16 count ----
  int cnt = 0, c16 = 0;
  {
    int r = 0;
    for (int jb = 0; jb < T; jb += 64) {
      int j = jb + lane;
      bool in = j < T;
      float d2 = 1e30f;
      unsigned orig = 0;
      if (in) {
        while (j >= rowstart[wv][r + 1]) ++r;
        int idx = j + rowadj[wv][r];
        float4 P = binned[pbase + idx];
        float dx = P.x - qx, dy = P.y - qy, dz = P.z - qz;
        d2 = dx * dx + dy * dy + dz * dz;
        orig = (unsigned)__float_as_int(P.w);
      }
      bool pred = in && (d2 <= 0.04f);
      unsigned long long mask = __ballot(pred);
      if (pred) {
        int mypos = cnt + __popcll(mask & ((1ull << lane) - 1ull));
        if (mypos < CAND_CAP)
          keys[wv][mypos] = ((unsigned long long)__float_as_uint(d2) << 32) | orig;
        int b = min((int)(d2 * 6400.0f), 255);
        atomicAdd(&hist32[wv][b], 1);
      }
      cnt += __popcll(mask);
      c16 += __popcll(__ballot(d2 <= 0.01f));
    }
  }
  __builtin_amdgcn_wave_barrier();
  __threadfence_block();
  const int cntf = min(cnt, CAND_CAP);
  const int k32 = min(32, cntf);
  const int k16 = min(16, c16);

  // ---- hist32 prefix scan; boundary bins for BOTH k32 and k16 ----
  {
    int h0 = hist32[wv][lane * 4 + 0];
    int h1 = hist32[wv][lane * 4 + 1];
    int h2 = hist32[wv][lane * 4 + 2];
    int h3 = hist32[wv][lane * 4 + 3];
    int c1 = h0 + h1, c2 = c1 + h2, c3 = c2 + h3;
    int is = c3;
#pragma unroll
    for (int o = 1; o < 64; o <<= 1) {
      int t = __shfl_up(is, o, 64);
      if (lane >= o) is += t;
    }
    int off = is - c3;
    int cum0 = off + h0, cum1 = off + c1, cum2 = off + c2, cum3 = off + c3;
    if (k32 > 0) {
      if (cum0 >= k32 && off  < k32) { bbin[wv][1] = lane * 4 + 0; msel[wv][1] = k32 - off;  }
      if (cum1 >= k32 && cum0 < k32) { bbin[wv][1] = lane * 4 + 1; msel[wv][1] = k32 - cum0; }
      if (cum2 >= k32 && cum1 < k32) { bbin[wv][1] = lane * 4 + 2; msel[wv][1] = k32 - cum1; }
      if (cum3 >= k32 && cum2 < k32) { bbin[wv][1] = lane * 4 + 3; msel[wv][1] = k32 - cum2; }
    }
    if (k16 > 0) {
      if (cum0 >= k16 && off  < k16) { bbin[wv][0] = lane * 4 + 0; msel[wv][0] = k16 - off;  }
      if (cum1 >= k16 && cum0 < k16) { bbin[wv][0] = lane * 4 + 1; msel[wv][0] = k16 - cum0; }
      if (cum2 >= k16 && cum1 < k16) { bbin[wv][0] = lane * 4 + 2; msel[wv][0] = k16 - cum1; }
      if (cum3 >= k16 && cum2 < k16) { bbin[wv][0] = lane * 4 + 3; msel[wv][0] = k16 - cum2; }
    }
  }
  __builtin_amdgcn_wave_barrier();
  __threadfence_block();
  const int b32b = bbin[wv][1];
  const int b16b = bbin[wv][0];

  // ---- collect boundary-bin keys (ballot compaction, both scales) ----
  int t32c = 0, t16c = 0;
  for (int base = 0; base < cntf; base += 64) {
    int i = base + lane;
    bool in = i < cntf;
    unsigned long long key = in ? keys[wv][i] : 0xFFFFFFFFFFFFFFFFull;
    float d2 = __uint_as_float((unsigned)(key >> 32));
    int b = min((int)(d2 * 6400.0f), 255);
    bool p1 = in && (b == b32b);
    unsigned long long m1 = __ballot(p1);
    if (p1) {
      int pos = t32c + __popcll(m1 & ((1ull << lane) - 1ull));
      if (pos < TMP_CAP) tmpb[wv][1][pos] = key;
    }
    t32c += __popcll(m1);
    bool p0 = in && (b == b16b);
    unsigned long long m0 = __ballot(p0);
    if (p0) {
      int pos = t16c + __popcll(m0 & ((1ull << lane) - 1ull));
      if (pos < TMP_CAP) tmpb[wv][0][pos] = key;
    }
    t16c += __popcll(m0);
  }
  __builtin_amdgcn_wave_barrier();
  __threadfence_block();

  // ---- rank-select m-th smallest key in each boundary bin ----
#pragma unroll
  for (int s = 0; s < 2; ++s) {
    const int k = s ? k32 : k16;
    if (k > 0) {
      const int h = min(s ? t32c : t16c, TMP_CAP);
      const int m = msel[wv][s];
      if (lane < h) {
        unsigned long long e = tmpb[wv][s][lane];
        int less = 0;
        for (int j = 0; j < h; ++j) less += (tmpb[wv][s][j] < e) ? 1 : 0;
        if (less == m - 1) Tkey[wv][s] = e;
      }
    }
  }
  __builtin_amdgcn_wave_barrier();
  __threadfence_block();
  const unsigned long long T32 = Tkey[wv][1];
  const unsigned long long T16 = Tkey[wv][0];

  // ---- compact selected neighbors (ballot); scale-0 subset into sel16 ----
  int sc = 0, sc16 = 0;
  for (int base = 0; base < cntf; base += 64) {
    int i = base + lane;
    bool in = i < cntf;
    unsigned long long key = in ? keys[wv][i] : 0xFFFFFFFFFFFFFFFFull;
    bool pred = in && (k32 > 0) && (key <= T32);
    bool pred16 = in && (k16 > 0) && (key <= T16);
    unsigned long long mask = __ballot(pred);
    unsigned long long mask16 = __ballot(pred16);
    unsigned long long lt = (1ull << lane) - 1ull;
    if (pred) {
      int pos = sc + __popcll(mask & lt);
      if (pos < 32) {
        int idx = (int)(key & 0xffffffffu);
        float rx = ppts[idx * 3 + 0] - qx;
        float ry = ppts[idx * 3 + 1] - qy;
        float rz = ppts[idx * 3 + 2] - qz;
        sel[wv][pos] = make_float4(rx, ry, rz, 0.0f);
        if (pred16) {
          int p16 = sc16 + __popcll(mask16 & lt);
          if (p16 < 16) sel16[wv][p16] = make_float4(rx, ry, rz, 0.0f);
        }
      }
    }
    sc += __popcll(mask);
    sc16 += __popcll(mask16);
  }
  __builtin_amdgcn_wave_barrier();
  __threadfence_block();
  const int nsel = min(sc, 32);
  const int n16 = min(sc16, 16);

  // ---- mask-free dual max-pool: lane covers 2 ch of each scale (packed f32x2) ----
  {
    const float* W1 = W1all + d.w1off[st];
    const float* b1 = b1all + d.b1off[st];
    const int c0 = lane * 2;
    const f32x2 wx0 = *(const f32x2*)(W1 + 0 * 128 + c0);
    const f32x2 wy0 = *(const f32x2*)(W1 + 1 * 128 + c0);
    const f32x2 wz0 = *(const f32x2*)(W1 + 2 * 128 + c0);
    const f32x2 wx1 = *(const f32x2*)(W1 + 384 + 0 * 128 + c0);
    const f32x2 wy1 = *(const f32x2*)(W1 + 384 + 1 * 128 + c0);
    const f32x2 wz1 = *(const f32x2*)(W1 + 384 + 2 * 128 + c0);
    const f32x2 bb0 = *(const f32x2*)(b1 + c0);
    const f32x2 bb1 = *(const f32x2*)(b1 + 128 + c0);
    f32x2 m0; m0.x = -INFINITY; m0.y = -INFINITY;
    f32x2 m1 = m0;
    for (int n = 0; n < n16; ++n) {
      float4 e = sel16[wv][n];
      f32x2 v = e.x * wx0 + e.y * wy0 + e.z * wz0;
      m0.x = fmaxf(m0.x, v.x); m0.y = fmaxf(m0.y, v.y);
    }
    for (int n = 0; n < nsel; ++n) {
      float4 e = sel[wv][n];
      f32x2 v = e.x * wx1 + e.y * wy1 + e.z * wz1;
      m1.x = fmaxf(m1.x, v.x); m1.y = fmaxf(m1.y, v.y);
    }
    // empty set: -inf + b -> relu -> 0 (matches reference)
    ushort2 o0, o1;
    o0.x = f2bf(fmaxf(m0.x + bb0.x, 0.0f));
    o0.y = f2bf(fmaxf(m0.y + bb0.y, 0.0f));
    o1.x = f2bf(fmaxf(m1.x + bb1.x, 0.0f));
    o1.y = f2bf(fmaxf(m1.y + bb1.y, 0.0f));
    unsigned short* fr = fbuf + (size_t)(d.foff[st] + qlocal) * 256;
    *(ushort2*)(fr + c0) = o0;
    *(ushort2*)(fr + 128 + c0) = o1;
  }
}

// ============================ MFMA GEMM kernel ============================
struct GemmDesc {
  const float* basep[3];
  float* outp[3];
  int blkstart[4];
  int nst[3];
  int foff[3][3];
  int w2off[3][3];
  int b2off[3][3];
};

__global__ __launch_bounds__(256) void bq_gemm_mfma(
    GemmDesc d, const unsigned short* __restrict__ W2F,
    const float* __restrict__ b2all, const unsigned short* __restrict__ fbuf) {
  __shared__ unsigned short ftile[32][264];
  const int tid = threadIdx.x, lane = tid & 63, wv = tid >> 6;

  int rg = 0;
  while ((int)blockIdx.x >= d.blkstart[rg + 1]) ++rg;
  const int qb = ((int)blockIdx.x - d.blkstart[rg]) * 32;

  f32x4 acc[2][4];
#pragma unroll
  for (int mt = 0; mt < 2; ++mt)
#pragma unroll
    for (int nt = 0; nt < 4; ++nt) acc[mt][nt] = (f32x4)0.0f;

  const int nst = d.nst[rg];
  for (int s = 0; s < nst; ++s) {
    __syncthreads();
    {
      const unsigned short* fsrc = fbuf + (size_t)(d.foff[rg][s] + qb) * 256;
#pragma unroll
      for (int i = 0; i < 4; ++i) {
        int c = tid + 256 * i;
        int row = c >> 5, k8 = (c & 31) * 8;
        *(uint4*)&ftile[row][k8] = *(const uint4*)(fsrc + (size_t)row * 256 + k8);
      }
    }
    __syncthreads();
    const unsigned short* wbase = W2F + d.w2off[rg][s];
#pragma unroll
    for (int kt = 0; kt < 8; ++kt) {
      const int koff = kt * 32 + (lane >> 4) * 8;
      bf16x8 a0 = *(const bf16x8*)&ftile[lane & 15][koff];
      bf16x8 a1 = *(const bf16x8*)&ftile[16 + (lane & 15)][koff];
#pragma unroll
      for (int nt = 0; nt < 4; ++nt) {
        int nb = wv * 4 + nt;
        bf16x8 bfr = *(const bf16x8*)(wbase + (size_t)((nb * 8 + kt) * 64 + lane) * 8);
        acc[0][nt] = __builtin_amdgcn_mfma_f32_16x16x32_bf16(a0, bfr, acc[0][nt], 0, 0, 0);
        acc[1][nt] = __builtin_amdgcn_mfma_f32_16x16x32_bf16(a1, bfr, acc[1][nt], 0, 0, 0);
      }
    }
  }

  float bb[4];
#pragma unroll
  for (int nt = 0; nt < 4; ++nt) {
    int c = wv * 64 + nt * 16 + (lane & 15);
    float sum = 0.0f;
    for (int s = 0; s < nst; ++s) sum += b2all[d.b2off[rg][s] + c];
    bb[nt] = sum;
  }

  const float* __restrict__ basep = d.basep[rg];
  float* __restrict__ outp = d.outp[rg];
#pragma unroll
  for (int mt = 0; mt < 2; ++mt) {
#pragma unroll
    for (int r = 0; r < 4; ++r) {
      int q = qb + mt * 16 + (lane >> 4) * 4 + r;
#pragma unroll
      for (int nt = 0; nt < 4; ++nt) {
        int c = wv * 64 + nt * 16 + (lane & 15);
        outp[(size_t)q * 256 + c] = basep[(size_t)q * 256 + c] + acc[mt][nt][r] + bb[nt];
      }
    }
  }
}

// ============================ fused fallback (tiny ws) ============================
__global__ __launch_bounds__(256) void init_out_kernel(
    const float* __restrict__ g, const float* __restrict__ s, const float* __restrict__ v,
    float* __restrict__ out) {
  const int NG = 4096 * 256, NS = 4096 * 256;
  int i = blockIdx.x * 256 + threadIdx.x;
  if (i < NG) out[i] = g[i];
  else if (i < NG + NS) out[i] = s[i - NG];
  else out[i] = v[i - NG - NS];
}

__global__ __launch_bounds__(256) void bq_stack_fused(
    const float* __restrict__ qpts,
    const float* __restrict__ ppts, int Np,
    const float* __restrict__ W1, const float* __restrict__ b1,
    const float* __restrict__ W2, const float* __restrict__ b2,
    float* __restrict__ out) {
  __shared__ unsigned long long keys[M_MAX];
  __shared__ int hist32[256];
  __shared__ int hist16[64];
  __shared__ unsigned long long tmpb[2][FTMP_CAP];
  __shared__ int tmpcnt[2];
  __shared__ float4 sel[32];
  __shared__ int selcnt;
  __shared__ float f_lds[256];
  __shared__ int cnt_s;
  __shared__ unsigned long long T_lds[2];
  __shared__ int bbin[2], msel[2];
  __shared__ int wsum[4];
  __shared__ float qsh[3];

  const int tid = threadIdx.x;
  const int lane = tid & 63;
  const int wv = tid >> 6;
  const int q = blockIdx.x;

  hist32[tid] = 0;
  if (tid < 64) hist16[tid] = 0;
  if (tid == 0) {
    cnt_s = 0; selcnt = 0; tmpcnt[0] = 0; tmpcnt[1] = 0;
    T_lds[0] = ~0ULL; T_lds[1] = ~0ULL;
    qsh[0] = qpts[q * 3 + 0]; qsh[1] = qpts[q * 3 + 1]; qsh[2] = qpts[q * 3 + 2];
  }
  __syncthreads();
  const float qx = qsh[0], qy = qsh[1], qz = qsh[2];

  const float4* pp4 = (const float4*)ppts;
  const int groups = Np >> 2;
  for (int gp = tid; gp < groups; gp += 256) {
    float4 A = pp4[gp * 3 + 0];
    float4 Bv = pp4[gp * 3 + 1];
    float4 C = pp4[gp * 3 + 2];
    float px[4] = {A.x, A.w, Bv.z, C.y};
    float py[4] = {A.y, Bv.x, Bv.w, C.z};
    float pz[4] = {A.z, Bv.y, C.x, C.w};
#pragma unroll
    for (int t = 0; t < 4; ++t) {
      float dx = px[t] - qx, dy = py[t] - qy, dz = pz[t] - qz;
      float d2 = dx * dx + dy * dy + dz * dz;
      if (d2 <= 0.04f) {
        int pos = atomicAdd(&cnt_s, 1);
        if (pos < M_MAX)
          keys[pos] = ((unsigned long long)__float_as_uint(d2) << 32) | (unsigned)(gp * 4 + t);
        int b = min((int)(d2 * 6400.0f), 255);
        atomicAdd(&hist32[b], 1);
        if (d2 <= 0.01f) atomicAdd(&hist16[min(b, 63)], 1);
      }
    }
  }
  __syncthreads();
  const int cnt = min(cnt_s, M_MAX);

  {
    int v = hist32[tid];
#pragma unroll
    for (int o = 1; o < 64; o <<= 1) {
      int t = __shfl_up(v, o, 64);
      if (lane >= o) v += t;
    }
    if (lane == 63) wsum[wv] = v;
    int v16 = 0;
    if (wv == 0) {
      v16 = hist16[lane];
#pragma unroll
      for (int o = 1; o < 64; o <<= 1) {
        int t = __shfl_up(v16, o, 64);
        if (lane >= o) v16 += t;
      }
    }
    __syncthreads();
    int off = 0;
    for (int w = 0; w < wv; ++w) off += wsum[w];
    hist32[tid] = v + off;
    if (wv == 0) hist16[lane] = v16;
    __syncthreads();
  }

  const int k32 = min(32, cnt);
  const int c16tot = hist16[63];
  const int k16 = min(16, c16tot);

  {
    int c = hist32[tid], cp = tid ? hist32[tid - 1] : 0;
    if (k32 > 0 && c >= k32 && cp < k32) { bbin[1] = tid; msel[1] = k32 - cp; }
    if (tid < 64) {
      int c6 = hist16[tid], cp6 = tid ? hist16[tid - 1] : 0;
      if (k16 > 0 && c6 >= k16 && cp6 < k16) { bbin[0] = tid; msel[0] = k16 - cp6; }
    }
  }
  __syncthreads();

  const int b32b = (k32 > 0) ? bbin[1] : -1;
  const int b16b = (k16 > 0) ? bbin[0] : -1;
  for (int i = tid; i < cnt; i += 256) {
    unsigned long long key = keys[i];
    float d2 = __uint_as_float((unsigned)(key >> 32));
    int b = min((int)(d2 * 6400.0f), 255);
    if (b == b32b) { int p = atomicAdd(&tmpcnt[1], 1); if (p < FTMP_CAP) tmpb[1][p] = key; }
    if (d2 <= 0.01f && min(b, 63) == b16b) {
      int p = atomicAdd(&tmpcnt[0], 1); if (p < FTMP_CAP) tmpb[0][p] = key;
    }
  }
  __syncthreads();

  if (wv < 2) {
    const int s = 1 - wv;
    const int k = s ? k32 : k16;
    if (k > 0) {
      const int h = min(tmpcnt[s], FTMP_CAP);
      const int m = msel[s];
      for (int base = 0; base < h; base += 64) {
        int ii = base + lane;
        if (ii < h) {
          unsigned long long e = tmpb[s][ii];
          int less = 0;
          for (int j = 0; j < h; ++j) less += (tmpb[s][j] < e) ? 1 : 0;
          if (less == m - 1) T_lds[s] = e;
        }
      }
    }
  }
  __syncthreads();

  {
    const unsigned long long T32 = (k32 > 0) ? T_lds[1] : 0ULL;
    const unsigned long long T16 = T_lds[0];
    for (int i = tid; i < cnt; i += 256) {
      unsigned long long key = keys[i];
      if (k32 > 0 && key <= T32) {
        float d2 = __uint_as_float((unsigned)(key >> 32));
        int idx = (int)(key & 0xffffffffu);
        float rx = ppts[idx * 3 + 0] - qx;
        float ry = ppts[idx * 3 + 1] - qy;
        float rz = ppts[idx * 3 + 2] - qz;
        bool f16 = (k16 > 0) && (d2 <= 0.01f) && (key <= T16);
        int slot = atomicAdd(&selcnt, 1);
        if (slot < 32) sel[slot] = make_float4(rx, ry, rz, f16 ? 1.0f : 0.0f);
      }
    }
  }
  __syncthreads();

  {
    const int nsel = min(selcnt, 32);
    const int scale = tid >> 7;
    const int h = tid & 127;
    const float w0 = W1[(scale * 3 + 0) * 128 + h];
    const float w1 = W1[(scale * 3 + 1) * 128 + h];
    const float w2 = W1[(scale * 3 + 2) * 128 + h];
    const float bb = b1[scale * 128 + h];
    float maxv = -INFINITY;
    for (int j = 0; j < nsel; ++j) {
      float4 e = sel[j];
      float val = e.x * w0 + e.y * w1 + e.z * w2;
      bool ok = scale ? true : (e.w > 0.5f);
      maxv = ok ? fmaxf(maxv, val) : maxv;
    }
    f_lds[tid] = fmaxf(maxv + bb, 0.0f);
  }
  __syncthreads();

  float* part = (float*)keys;
  {
    float4 acc = make_float4(0.f, 0.f, 0.f, 0.f);
    for (int r = 0; r < 64; ++r) {
      float fv = f_lds[wv * 64 + r];
      float4 w = ((const float4*)W2)[(wv * 64 + r) * 64 + lane];
      acc.x += fv * w.x; acc.y += fv * w.y; acc.z += fv * w.z; acc.w += fv * w.w;
    }
    ((float4*)part)[wv * 64 + lane] = acc;
  }
  __syncthreads();
  {
    float sum = part[0 * 256 + tid] + part[1 * 256 + tid] + part[2 * 256 + tid] +
                part[3 * 256 + tid] + b2[tid];
    out[q * 256 + tid] += sum;
  }
}

// ============================ launch ============================
extern "C" void kernel_launch(void* const* d_in, const int* in_sizes, int n_in,
                              void* d_out, int out_size, void* d_ws, size_t ws_size,
                              hipStream_t stream) {
  const float* g      = (const float*)d_in[0];
  const float* s      = (const float*)d_in[1];
  const float* v      = (const float*)d_in[2];
  const float* geo_t  = (const float*)d_in[3];
  const float* surf_t = (const float*)d_in[4];
  const float* vol_t  = (const float*)d_in[5];
  const float* W1     = (const float*)d_in[6];
  const float* b1     = (const float*)d_in[7];
  const float* W2     = (const float*)d_in[8];
  const float* b2     = (const float*)d_in[9];
  float* out = (float*)d_out;

  const int NG = 4096, NS = 4096, NV = 8192;
  float* out_g = out;
  float* out_s = out + NG * 256;
  float* out_v = out + (NG + NS) * 256;

  const int stackid[7] = {0, 3, 4, 1, 5, 2, 6};
  const float* qp[7]   = {g, g, g, s, s, v, v};
  const int    nq[7]   = {NG, NG, NG, NS, NS, NV, NV};
  const int    pset[7] = {0, 1, 2, 1, 0, 2, 0};
  const float* praw[3] = {g, s, v};
  const int    setbase[3] = {0, 4096, 8192};

  const size_t FB = (size_t)36864 * 256 * sizeof(unsigned short);
  const size_t WT = (size_t)7 * 256 * 256 * sizeof(unsigned short);
  const size_t GI = (size_t)3 * 1024 * sizeof(int);
  const size_t need = FB + WT + GI + (size_t)16384 * sizeof(float4);

  if (ws_size >= need) {
    unsigned short* fbuf = (unsigned short*)d_ws;
    unsigned short* W2F  = (unsigned short*)((char*)d_ws + FB);
    int* starts = (int*)((char*)d_ws + FB + WT);
    float4* binned = (float4*)((char*)d_ws + FB + WT + GI);

    hipLaunchKernelGGL(prep_kernel, dim3(227), dim3(256), 0, stream,
                       g, s, v, W2, W2F, starts, binned);

    SelDesc sd;
    int blk = 0, frow = 0;
    int foffs[7];
    for (int i = 0; i < 7; ++i) {
      sd.qptr[i] = qp[i];
      sd.pptr[i] = praw[pset[i]];
      sd.pbase[i] = setbase[pset[i]];
      sd.soff[i] = pset[i] * 1024;
      sd.w1off[i] = stackid[i] * 768;
      sd.b1off[i] = stackid[i] * 256;
      sd.foff[i] = frow;
      foffs[i] = frow;
      sd.blkstart[i] = blk;
      blk += nq[i] / 4;
      frow += nq[i];
    }
    sd.blkstart[7] = blk;
    hipLaunchKernelGGL(bq_select_grid, dim3(blk), dim3(256), 0, stream,
                       sd, W1, b1, binned, starts, fbuf);

    GemmDesc gd;
    gd.basep[0] = geo_t;  gd.outp[0] = out_g;
    gd.basep[1] = surf_t; gd.outp[1] = out_s;
    gd.basep[2] = vol_t;  gd.outp[2] = out_v;
    gd.blkstart[0] = 0;
    gd.blkstart[1] = NG / 32;
    gd.blkstart[2] = NG / 32 + NS / 32;
    gd.blkstart[3] = NG / 32 + NS / 32 + NV / 32;
    gd.nst[0] = 3; gd.nst[1] = 2; gd.nst[2] = 2;
    const int ridx[3][3] = {{0, 1, 2}, {3, 4, -1}, {5, 6, -1}};
    for (int r = 0; r < 3; ++r)
      for (int t = 0; t < gd.nst[r]; ++t) {
        int i = ridx[r][t];
        gd.foff[r][t] = foffs[i];
        gd.w2off[r][t] = stackid[i] * 256 * 256;
        gd.b2off[r][t] = stackid[i] * 256;
      }
    hipLaunchKernelGGL(bq_gemm_mfma, dim3(gd.blkstart[3]), dim3(256), 0, stream,
                       gd, W2F, b2, fbuf);
  } else {
    const int total = (NG + NS + NV) * 256;
    hipLaunchKernelGGL(init_out_kernel, dim3(total / 256), dim3(256), 0, stream,
                       geo_t, surf_t, vol_t, out);
    auto launch = [&](int stack, const float* qp_, int Nq, const float* pp_, int Np, float* o) {
      hipLaunchKernelGGL(bq_stack_fused, dim3(Nq), dim3(256), 0, stream,
                         qp_, pp_, Np, W1 + stack * 768, b1 + stack * 256,
                         W2 + stack * 256 * 256, b2 + stack * 256, o);
    };
    launch(0, g, NG, g, NG, out_g);
    launch(3, g, NG, s, NS, out_g);
    launch(4, g, NG, v, NV, out_g);
    launch(1, s, NS, s, NS, out_s);
    launch(5, s, NS, g, NG, out_s);
    launch(2, v, NV, v, NV, out_v);
    launch(6, v, NV, g, NG, out_v);
  }
}

// Round 11
// 212.728 us; speedup vs baseline: 1.0990x; 1.0558x over previous
//
#include <hip/hip_runtime.h>

#define CAND_CAP 320
#define TMP_CAP 32
#define M_MAX 1024
#define FTMP_CAP 128

typedef __attribute__((ext_vector_type(8))) short bf16x8;
typedef __attribute__((ext_vector_type(4))) float f32x4;
typedef __attribute__((ext_vector_type(2))) float f32x2;

__device__ __forceinline__ unsigned short f2bf(float x) {
  unsigned u = __float_as_uint(x);
  unsigned r = (u + 0x7fffu + ((u >> 16) & 1u)) >> 16;
  return (unsigned short)r;
}

__device__ __forceinline__ int cell_of(float x, float y, float z) {
  int cx = min((int)(x * 10.0f), 9);
  int cy = min((int)(y * 10.0f), 9);
  int cz = min((int)(z * 10.0f), 9);
  return cz * 100 + cy * 10 + cx;
}

// ============================ fused prep kernel ============================
__global__ __launch_bounds__(256) void prep_kernel(
    const float* __restrict__ g, const float* __restrict__ s, const float* __restrict__ v,
    const float* __restrict__ W2, unsigned short* __restrict__ W2F,
    int* __restrict__ starts, float4* __restrict__ binned) {
  const int b = blockIdx.x;
  if (b < 3) {
    __shared__ int hist[1024];
    __shared__ int wsum[4];
    const int tid = threadIdx.x, lane = tid & 63, wv = tid >> 6;
    const float* p = (b == 0) ? g : (b == 1) ? s : v;
    const int Np = (b == 2) ? 8192 : 4096;
    const int base = (b == 0) ? 0 : (b == 1) ? 4096 : 8192;

    for (int i = tid; i < 1024; i += 256) hist[i] = 0;
    __syncthreads();
    for (int i = tid; i < Np; i += 256) {
      float x = p[i * 3 + 0], y = p[i * 3 + 1], z = p[i * 3 + 2];
      atomicAdd(&hist[cell_of(x, y, z)], 1);
    }
    __syncthreads();
    int h0 = hist[tid * 4 + 0], h1 = hist[tid * 4 + 1];
    int h2 = hist[tid * 4 + 2], h3 = hist[tid * 4 + 3];
    int c1 = h0 + h1, c2 = c1 + h2, c3 = c2 + h3;
    int is = c3;
#pragma unroll
    for (int o = 1; o < 64; o <<= 1) {
      int t = __shfl_up(is, o, 64);
      if (lane >= o) is += t;
    }
    if (lane == 63) wsum[wv] = is;
    __syncthreads();
    int off = is - c3;
    for (int w = 0; w < wv; ++w) off += wsum[w];
    __syncthreads();
    hist[tid * 4 + 0] = off;
    hist[tid * 4 + 1] = off + h0;
    hist[tid * 4 + 2] = off + c1;
    hist[tid * 4 + 3] = off + c2;
    starts[b * 1024 + tid * 4 + 0] = off;
    starts[b * 1024 + tid * 4 + 1] = off + h0;
    starts[b * 1024 + tid * 4 + 2] = off + c1;
    starts[b * 1024 + tid * 4 + 3] = off + c2;
    __syncthreads();
    for (int i = tid; i < Np; i += 256) {
      float x = p[i * 3 + 0], y = p[i * 3 + 1], z = p[i * 3 + 2];
      int pos = atomicAdd(&hist[cell_of(x, y, z)], 1);
      binned[base + pos] = make_float4(x, y, z, __int_as_float(i));
    }
  } else {
    int t = (b - 3) * 256 + threadIdx.x;
    int s_ = t >> 13;
    int rem = t & 8191;
    int nb = rem >> 9;
    int rem2 = rem & 511;
    int kt = rem2 >> 6;
    int l = rem2 & 63;
    int n = nb * 16 + (l & 15);
    int k0 = kt * 32 + (l >> 4) * 8;
    bf16x8 vfr;
#pragma unroll
    for (int j = 0; j < 8; ++j)
      vfr[j] = (short)f2bf(W2[((size_t)s_ * 256 + (k0 + j)) * 256 + n]);
    *(bf16x8*)(W2F + (size_t)t * 8) = vfr;
  }
}

// ============================ merged select kernel ============================
struct SelDesc {
  const float* qptr[7];
  const float* pptr[7];
  int pbase[7];
  int soff[7];
  int w1off[7];
  int b1off[7];
  int foff[7];
  int blkstart[8];
};

__global__ __launch_bounds__(256, 8) void bq_select_grid(
    SelDesc d, const float* __restrict__ W1all, const float* __restrict__ b1all,
    const float4* __restrict__ binned, const int* __restrict__ starts,
    unsigned short* __restrict__ fbuf) {
  __shared__ unsigned long long keys[4][CAND_CAP];   // 10240 B
  __shared__ unsigned long long tmpb[4][2][TMP_CAP]; // 2048 B
  __shared__ unsigned long long Tkey[4][2];          // 64 B
  __shared__ int hist32[4][256];                     // 4096 B
  __shared__ int bbin[4][2];                         // 32 B
  __shared__ int msel[4][2];                         // 32 B
  __shared__ float4 sel[4][32];                      // 2048 B
  __shared__ float4 sel16[4][16];                    // 1024 B
  __shared__ int rowstart[4][28];                    // 448 B
  __shared__ int rowadj[4][28];                      // 448 B  -> 20480 B total

  const int tid = threadIdx.x, lane = tid & 63, wv = tid >> 6;

  int st = 0;
  while ((int)blockIdx.x >= d.blkstart[st + 1]) ++st;
  const int qlocal = ((int)blockIdx.x - d.blkstart[st]) * 4 + wv;
  const float* qpts = d.qptr[st];
  const float* ppts = d.pptr[st];
  const int pbase = d.pbase[st];
  const int soff = d.soff[st];

#pragma unroll
  for (int i = 0; i < 4; ++i) hist32[wv][lane + 64 * i] = 0;
  if (lane == 0) {
    Tkey[wv][0] = 0; Tkey[wv][1] = 0;
    bbin[wv][0] = -1; bbin[wv][1] = -1;
    msel[wv][0] = 0; msel[wv][1] = 0;
  }
  const float qx = qpts[qlocal * 3 + 0];
  const float qy = qpts[qlocal * 3 + 1];
  const float qz = qpts[qlocal * 3 + 2];

  // ---- flattened row table with per-row x-chord culling ----
  const int cy0 = max(0, (int)floorf((qy - 0.2f) * 10.0f));
  const int cy1 = min(9, (int)floorf((qy + 0.2f) * 10.0f));
  const int cz0 = max(0, (int)floorf((qz - 0.2f) * 10.0f));
  const int cz1 = min(9, (int)floorf((qz + 0.2f) * 10.0f));
  const int ncy = cy1 - cy0 + 1;
  const int nrows = (cz1 - cz0 + 1) * ncy;

  int len = 0, beg = 0;
  if (lane < nrows) {
    int czi = lane / ncy;
    int cz = cz0 + czi;
    int cy = cy0 + (lane - czi * ncy);
    float lo = cz * 0.1f;
    float dz = fmaxf(fmaxf(lo - qz, qz - (lo + 0.1f)), 0.0f);
    float loy = cy * 0.1f;
    float dy = fmaxf(fmaxf(loy - qy, qy - (loy + 0.1f)), 0.0f);
    float dyz2 = dz * dz + dy * dy;
    if (dyz2 <= 0.04f) {
      float xr = __builtin_sqrtf(0.04f - dyz2);
      int cxlo = max(0, (int)floorf((qx - xr) * 10.0f));
      int cxhi = min(9, (int)floorf((qx + xr) * 10.0f));
      int row = cz * 100 + cy * 10;
      beg = starts[soff + row + cxlo];
      int end = starts[soff + row + cxhi + 1];
      len = end - beg;
    }
  }
  int incl = len;
#pragma unroll
  for (int o = 1; o < 64; o <<= 1) {
    int t = __shfl_up(incl, o, 64);
    if (lane >= o) incl += t;
  }
  const int T = __shfl(incl, 63, 64);
  int excl = incl - len;
  if (lane <= nrows) { rowstart[wv][lane] = excl; rowadj[wv][lane] = beg - excl; }
  __builtin_amdgcn_wave_barrier();
  __threadfence_block();

  // ---- software-pipelined dense scan: prefetch next gather before processing ----
  int cnt = 0, c16 = 0;
  {
    int r = 0;
    float4 Pcur = make_float4(1e30f, 1e30f, 1e30f, 0.0f);
    bool incur = lane < T;
    if (incur) {
      while (lane >= rowstart[wv][r + 1]) ++r;
      Pcur = binned[pbase + lane + rowadj[wv][r]];
    }
    for (int jb = 0; jb < T; jb += 64) {
      // prefetch next iteration's point
      int rn = r;
      int jn = jb + 64 + lane;
      bool innext = jn < T;
      float4 Pnext = Pcur;
      if (innext) {
        while (jn >= rowstart[wv][rn + 1]) ++rn;
        Pnext = binned[pbase + jn + rowadj[wv][rn]];
      }
      // process current
      bool in = jb + lane < T;
      float dx = Pcur.x - qx, dy = Pcur.y - qy, dz = Pcur.z - qz;
      float d2 = in ? (dx * dx + dy * dy + dz * dz) : 1e30f;
      bool pred = in && (d2 <= 0.04f);
      unsigned long long mask = __ballot(pred);
      if (pred) {
        int mypos = cnt + __popcll(mask & ((1ull << lane) - 1ull));
        if (mypos < CAND_CAP)
          keys[wv][mypos] = ((unsigned long long)__float_as_uint(d2) << 32) |
                            (unsigned)__float_as_int(Pcur.w);
        int b = min((int)(d2 * 6400.0f), 255);
        atomicAdd(&hist32[wv][b], 1);
      }
      cnt += __popcll(mask);
      c16 += __popcll(__ballot(d2 <= 0.01f));
      Pcur = Pnext;
      r = rn;
    }
  }
  __builtin_amdgcn_wave_barrier();
  __threadfence_block();
  const int cntf = min(cnt, CAND_CAP);
  const int k32 = min(32, cntf);
  const int k16 = min(16, c16);

  // ---- hist32 prefix scan; boundary bins for BOTH k32 and k16 ----
  {
    int h0 = hist32[wv][lane * 4 + 0];
    int h1 = hist32[wv][lane * 4 + 1];
    int h2 = hist32[wv][lane * 4 + 2];
    int h3 = hist32[wv][lane * 4 + 3];
    int c1 = h0 + h1, c2 = c1 + h2, c3 = c2 + h3;
    int is = c3;
#pragma unroll
    for (int o = 1; o < 64; o <<= 1) {
      int t = __shfl_up(is, o, 64);
      if (lane >= o) is += t;
    }
    int off = is - c3;
    int cum0 = off + h0, cum1 = off + c1, cum2 = off + c2, cum3 = off + c3;
    if (k32 > 0) {
      if (cum0 >= k32 && off  < k32) { bbin[wv][1] = lane * 4 + 0; msel[wv][1] = k32 - off;  }
      if (cum1 >= k32 && cum0 < k32) { bbin[wv][1] = lane * 4 + 1; msel[wv][1] = k32 - cum0; }
      if (cum2 >= k32 && cum1 < k32) { bbin[wv][1] = lane * 4 + 2; msel[wv][1] = k32 - cum1; }
      if (cum3 >= k32 && cum2 < k32) { bbin[wv][1] = lane * 4 + 3; msel[wv][1] = k32 - cum2; }
    }
    if (k16 > 0) {
      if (cum0 >= k16 && off  < k16) { bbin[wv][0] = lane * 4 + 0; msel[wv][0] = k16 - off;  }
      if (cum1 >= k16 && cum0 < k16) { bbin[wv][0] = lane * 4 + 1; msel[wv][0] = k16 - cum0; }
      if (cum2 >= k16 && cum1 < k16) { bbin[wv][0] = lane * 4 + 2; msel[wv][0] = k16 - cum1; }
      if (cum3 >= k16 && cum2 < k16) { bbin[wv][0] = lane * 4 + 3; msel[wv][0] = k16 - cum2; }
    }
  }
  __builtin_amdgcn_wave_barrier();
  __threadfence_block();
  const int b32b = bbin[wv][1];
  const int b16b = bbin[wv][0];

  // ---- collect boundary-bin keys (ballot compaction, both scales) ----
  int t32c = 0, t16c = 0;
  for (int base = 0; base < cntf; base += 64) {
    int i = base + lane;
    bool in = i < cntf;
    unsigned long long key = in ? keys[wv][i] : 0xFFFFFFFFFFFFFFFFull;
    float d2 = __uint_as_float((unsigned)(key >> 32));
    int b = min((int)(d2 * 6400.0f), 255);
    bool p1 = in && (b == b32b);
    unsigned long long m1 = __ballot(p1);
    if (p1) {
      int pos = t32c + __popcll(m1 & ((1ull << lane) - 1ull));
      if (pos < TMP_CAP) tmpb[wv][1][pos] = key;
    }
    t32c += __popcll(m1);
    bool p0 = in && (b == b16b);
    unsigned long long m0 = __ballot(p0);
    if (p0) {
      int pos = t16c + __popcll(m0 & ((1ull << lane) - 1ull));
      if (pos < TMP_CAP) tmpb[wv][0][pos] = key;
    }
    t16c += __popcll(m0);
  }
  __builtin_amdgcn_wave_barrier();
  __threadfence_block();

  // ---- rank-select m-th smallest key in each boundary bin ----
#pragma unroll
  for (int s = 0; s < 2; ++s) {
    const int k = s ? k32 : k16;
    if (k > 0) {
      const int h = min(s ? t32c : t16c, TMP_CAP);
      const int m = msel[wv][s];
      if (lane < h) {
        unsigned long long e = tmpb[wv][s][lane];
        int less = 0;
        for (int j = 0; j < h; ++j) less += (tmpb[wv][s][j] < e) ? 1 : 0;
        if (less == m - 1) Tkey[wv][s] = e;
      }
    }
  }
  __builtin_amdgcn_wave_barrier();
  __threadfence_block();
  const unsigned long long T32 = Tkey[wv][1];
  const unsigned long long T16 = Tkey[wv][0];

  // ---- compact selected neighbors (ballot); scale-0 subset into sel16 ----
  int sc = 0, sc16 = 0;
  for (int base = 0; base < cntf; base += 64) {
    int i = base + lane;
    bool in = i < cntf;
    unsigned long long key = in ? keys[wv][i] : 0xFFFFFFFFFFFFFFFFull;
    bool pred = in && (k32 > 0) && (key <= T32);
    bool pred16 = in && (k16 > 0) && (key <= T16);
    unsigned long long mask = __ballot(pred);
    unsigned long long mask16 = __ballot(pred16);
    unsigned long long lt = (1ull << lane) - 1ull;
    if (pred) {
      int pos = sc + __popcll(mask & lt);
      if (pos < 32) {
        int idx = (int)(key & 0xffffffffu);
        float rx = ppts[idx * 3 + 0] - qx;
        float ry = ppts[idx * 3 + 1] - qy;
        float rz = ppts[idx * 3 + 2] - qz;
        sel[wv][pos] = make_float4(rx, ry, rz, 0.0f);
        if (pred16) {
          int p16 = sc16 + __popcll(mask16 & lt);
          if (p16 < 16) sel16[wv][p16] = make_float4(rx, ry, rz, 0.0f);
        }
      }
    }
    sc += __popcll(mask);
    sc16 += __popcll(mask16);
  }
  __builtin_amdgcn_wave_barrier();
  __threadfence_block();
  const int nsel = min(sc, 32);
  const int n16 = min(sc16, 16);

  // ---- mask-free dual max-pool: lane covers 2 ch of each scale (packed f32x2) ----
  {
    const float* W1 = W1all + d.w1off[st];
    const float* b1 = b1all + d.b1off[st];
    const int c0 = lane * 2;
    const f32x2 wx0 = *(const f32x2*)(W1 + 0 * 128 + c0);
    const f32x2 wy0 = *(const f32x2*)(W1 + 1 * 128 + c0);
    const f32x2 wz0 = *(const f32x2*)(W1 + 2 * 128 + c0);
    const f32x2 wx1 = *(const f32x2*)(W1 + 384 + 0 * 128 + c0);
    const f32x2 wy1 = *(const f32x2*)(W1 + 384 + 1 * 128 + c0);
    const f32x2 wz1 = *(const f32x2*)(W1 + 384 + 2 * 128 + c0);
    const f32x2 bb0 = *(const f32x2*)(b1 + c0);
    const f32x2 bb1 = *(const f32x2*)(b1 + 128 + c0);
    f32x2 m0; m0.x = -INFINITY; m0.y = -INFINITY;
    f32x2 m1 = m0;
    for (int n = 0; n < n16; ++n) {
      float4 e = sel16[wv][n];
      f32x2 v = e.x * wx0 + e.y * wy0 + e.z * wz0;
      m0.x = fmaxf(m0.x, v.x); m0.y = fmaxf(m0.y, v.y);
    }
    for (int n = 0; n < nsel; ++n) {
      float4 e = sel[wv][n];
      f32x2 v = e.x * wx1 + e.y * wy1 + e.z * wz1;
      m1.x = fmaxf(m1.x, v.x); m1.y = fmaxf(m1.y, v.y);
    }
    ushort2 o0, o1;
    o0.x = f2bf(fmaxf(m0.x + bb0.x, 0.0f));
    o0.y = f2bf(fmaxf(m0.y + bb0.y, 0.0f));
    o1.x = f2bf(fmaxf(m1.x + bb1.x, 0.0f));
    o1.y = f2bf(fmaxf(m1.y + bb1.y, 0.0f));
    unsigned short* fr = fbuf + (size_t)(d.foff[st] + qlocal) * 256;
    *(ushort2*)(fr + c0) = o0;
    *(ushort2*)(fr + 128 + c0) = o1;
  }
}

// ============================ MFMA GEMM kernel ============================
struct GemmDesc {
  const float* basep[3];
  float* outp[3];
  int blkstart[4];
  int nst[3];
  int foff[3][3];
  int w2off[3][3];
  int b2off[3][3];
};

__global__ __launch_bounds__(256) void bq_gemm_mfma(
    GemmDesc d, const unsigned short* __restrict__ W2F,
    const float* __restrict__ b2all, const unsigned short* __restrict__ fbuf) {
  __shared__ unsigned short ftile[32][264];
  const int tid = threadIdx.x, lane = tid & 63, wv = tid >> 6;

  int rg = 0;
  while ((int)blockIdx.x >= d.blkstart[rg + 1]) ++rg;
  const int qb = ((int)blockIdx.x - d.blkstart[rg]) * 32;

  f32x4 acc[2][4];
#pragma unroll
  for (int mt = 0; mt < 2; ++mt)
#pragma unroll
    for (int nt = 0; nt < 4; ++nt) acc[mt][nt] = (f32x4)0.0f;

  const int nst = d.nst[rg];
  for (int s = 0; s < nst; ++s) {
    __syncthreads();
    {
      const unsigned short* fsrc = fbuf + (size_t)(d.foff[rg][s] + qb) * 256;
#pragma unroll
      for (int i = 0; i < 4; ++i) {
        int c = tid + 256 * i;
        int row = c >> 5, k8 = (c & 31) * 8;
        *(uint4*)&ftile[row][k8] = *(const uint4*)(fsrc + (size_t)row * 256 + k8);
      }
    }
    __syncthreads();
    const unsigned short* wbase = W2F + d.w2off[rg][s];
#pragma unroll
    for (int kt = 0; kt < 8; ++kt) {
      const int koff = kt * 32 + (lane >> 4) * 8;
      bf16x8 a0 = *(const bf16x8*)&ftile[lane & 15][koff];
      bf16x8 a1 = *(const bf16x8*)&ftile[16 + (lane & 15)][koff];
#pragma unroll
      for (int nt = 0; nt < 4; ++nt) {
        int nb = wv * 4 + nt;
        bf16x8 bfr = *(const bf16x8*)(wbase + (size_t)((nb * 8 + kt) * 64 + lane) * 8);
        acc[0][nt] = __builtin_amdgcn_mfma_f32_16x16x32_bf16(a0, bfr, acc[0][nt], 0, 0, 0);
        acc[1][nt] = __builtin_amdgcn_mfma_f32_16x16x32_bf16(a1, bfr, acc[1][nt], 0, 0, 0);
      }
    }
  }

  float bb[4];
#pragma unroll
  for (int nt = 0; nt < 4; ++nt) {
    int c = wv * 64 + nt * 16 + (lane & 15);
    float sum = 0.0f;
    for (int s = 0; s < nst; ++s) sum += b2all[d.b2off[rg][s] + c];
    bb[nt] = sum;
  }

  const float* __restrict__ basep = d.basep[rg];
  float* __restrict__ outp = d.outp[rg];
#pragma unroll
  for (int mt = 0; mt < 2; ++mt) {
#pragma unroll
    for (int r = 0; r < 4; ++r) {
      int q = qb + mt * 16 + (lane >> 4) * 4 + r;
#pragma unroll
      for (int nt = 0; nt < 4; ++nt) {
        int c = wv * 64 + nt * 16 + (lane & 15);
        outp[(size_t)q * 256 + c] = basep[(size_t)q * 256 + c] + acc[mt][nt][r] + bb[nt];
      }
    }
  }
}

// ============================ fused fallback (tiny ws) ============================
__global__ __launch_bounds__(256) void init_out_kernel(
    const float* __restrict__ g, const float* __restrict__ s, const float* __restrict__ v,
    float* __restrict__ out) {
  const int NG = 4096 * 256, NS = 4096 * 256;
  int i = blockIdx.x * 256 + threadIdx.x;
  if (i < NG) out[i] = g[i];
  else if (i < NG + NS) out[i] = s[i - NG];
  else out[i] = v[i - NG - NS];
}

__global__ __launch_bounds__(256) void bq_stack_fused(
    const float* __restrict__ qpts,
    const float* __restrict__ ppts, int Np,
    const float* __restrict__ W1, const float* __restrict__ b1,
    const float* __restrict__ W2, const float* __restrict__ b2,
    float* __restrict__ out) {
  __shared__ unsigned long long keys[M_MAX];
  __shared__ int hist32[256];
  __shared__ int hist16[64];
  __shared__ unsigned long long tmpb[2][FTMP_CAP];
  __shared__ int tmpcnt[2];
  __shared__ float4 sel[32];
  __shared__ int selcnt;
  __shared__ float f_lds[256];
  __shared__ int cnt_s;
  __shared__ unsigned long long T_lds[2];
  __shared__ int bbin[2], msel[2];
  __shared__ int wsum[4];
  __shared__ float qsh[3];

  const int tid = threadIdx.x;
  const int lane = tid & 63;
  const int wv = tid >> 6;
  const int q = blockIdx.x;

  hist32[tid] = 0;
  if (tid < 64) hist16[tid] = 0;
  if (tid == 0) {
    cnt_s = 0; selcnt = 0; tmpcnt[0] = 0; tmpcnt[1] = 0;
    T_lds[0] = ~0ULL; T_lds[1] = ~0ULL;
    qsh[0] = qpts[q * 3 + 0]; qsh[1] = qpts[q * 3 + 1]; qsh[2] = qpts[q * 3 + 2];
  }
  __syncthreads();
  const float qx = qsh[0], qy = qsh[1], qz = qsh[2];

  const float4* pp4 = (const float4*)ppts;
  const int groups = Np >> 2;
  for (int gp = tid; gp < groups; gp += 256) {
    float4 A = pp4[gp * 3 + 0];
    float4 Bv = pp4[gp * 3 + 1];
    float4 C = pp4[gp * 3 + 2];
    float px[4] = {A.x, A.w, Bv.z, C.y};
    float py[4] = {A.y, Bv.x, Bv.w, C.z};
    float pz[4] = {A.z, Bv.y, C.x, C.w};
#pragma unroll
    for (int t = 0; t < 4; ++t) {
      float dx = px[t] - qx, dy = py[t] - qy, dz = pz[t] - qz;
      float d2 = dx * dx + dy * dy + dz * dz;
      if (d2 <= 0.04f) {
        int pos = atomicAdd(&cnt_s, 1);
        if (pos < M_MAX)
          keys[pos] = ((unsigned long long)__float_as_uint(d2) << 32) | (unsigned)(gp * 4 + t);
        int b = min((int)(d2 * 6400.0f), 255);
        atomicAdd(&hist32[b], 1);
        if (d2 <= 0.01f) atomicAdd(&hist16[min(b, 63)], 1);
      }
    }
  }
  __syncthreads();
  const int cnt = min(cnt_s, M_MAX);

  {
    int v = hist32[tid];
#pragma unroll
    for (int o = 1; o < 64; o <<= 1) {
      int t = __shfl_up(v, o, 64);
      if (lane >= o) v += t;
    }
    if (lane == 63) wsum[wv] = v;
    int v16 = 0;
    if (wv == 0) {
      v16 = hist16[lane];
#pragma unroll
      for (int o = 1; o < 64; o <<= 1) {
        int t = __shfl_up(v16, o, 64);
        if (lane >= o) v16 += t;
      }
    }
    __syncthreads();
    int off = 0;
    for (int w = 0; w < wv; ++w) off += wsum[w];
    hist32[tid] = v + off;
    if (wv == 0) hist16[lane] = v16;
    __syncthreads();
  }

  const int k32 = min(32, cnt);
  const int c16tot = hist16[63];
  const int k16 = min(16, c16tot);

  {
    int c = hist32[tid], cp = tid ? hist32[tid - 1] : 0;
    if (k32 > 0 && c >= k32 && cp < k32) { bbin[1] = tid; msel[1] = k32 - cp; }
    if (tid < 64) {
      int c6 = hist16[tid], cp6 = tid ? hist16[tid - 1] : 0;
      if (k16 > 0 && c6 >= k16 && cp6 < k16) { bbin[0] = tid; msel[0] = k16 - cp6; }
    }
  }
  __syncthreads();

  const int b32b = (k32 > 0) ? bbin[1] : -1;
  const int b16b = (k16 > 0) ? bbin[0] : -1;
  for (int i = tid; i < cnt; i += 256) {
    unsigned long long key = keys[i];
    float d2 = __uint_as_float((unsigned)(key >> 32));
    int b = min((int)(d2 * 6400.0f), 255);
    if (b == b32b) { int p = atomicAdd(&tmpcnt[1], 1); if (p < FTMP_CAP) tmpb[1][p] = key; }
    if (d2 <= 0.01f && min(b, 63) == b16b) {
      int p = atomicAdd(&tmpcnt[0], 1); if (p < FTMP_CAP) tmpb[0][p] = key;
    }
  }
  __syncthreads();

  if (wv < 2) {
    const int s = 1 - wv;
    const int k = s ? k32 : k16;
    if (k > 0) {
      const int h = min(tmpcnt[s], FTMP_CAP);
      const int m = msel[s];
      for (int base = 0; base < h; base += 64) {
        int ii = base + lane;
        if (ii < h) {
          unsigned long long e = tmpb[s][ii];
          int less = 0;
          for (int j = 0; j < h; ++j) less += (tmpb[s][j] < e) ? 1 : 0;
          if (less == m - 1) T_lds[s] = e;
        }
      }
    }
  }
  __syncthreads();

  {
    const unsigned long long T32 = (k32 > 0) ? T_lds[1] : 0ULL;
    const unsigned long long T16 = T_lds[0];
    for (int i = tid; i < cnt; i += 256) {
      unsigned long long key = keys[i];
      if (k32 > 0 && key <= T32) {
        float d2 = __uint_as_float((unsigned)(key >> 32));
        int idx = (int)(key & 0xffffffffu);
        float rx = ppts[idx * 3 + 0] - qx;
        float ry = ppts[idx * 3 + 1] - qy;
        float rz = ppts[idx * 3 + 2] - qz;
        bool f16 = (k16 > 0) && (d2 <= 0.01f) && (key <= T16);
        int slot = atomicAdd(&selcnt, 1);
        if (slot < 32) sel[slot] = make_float4(rx, ry, rz, f16 ? 1.0f : 0.0f);
      }
    }
  }
  __syncthreads();

  {
    const int nsel = min(selcnt, 32);
    const int scale = tid >> 7;
    const int h = tid & 127;
    const float w0 = W1[(scale * 3 + 0) * 128 + h];
    const float w1 = W1[(scale * 3 + 1) * 128 + h];
    const float w2 = W1[(scale * 3 + 2) * 128 + h];
    const float bb = b1[scale * 128 + h];
    float maxv = -INFINITY;
    for (int j = 0; j < nsel; ++j) {
      float4 e = sel[j];
      float val = e.x * w0 + e.y * w1 + e.z * w2;
      bool ok = scale ? true : (e.w > 0.5f);
      maxv = ok ? fmaxf(maxv, val) : maxv;
    }
    f_lds[tid] = fmaxf(maxv + bb, 0.0f);
  }
  __syncthreads();

  float* part = (float*)keys;
  {
    float4 acc = make_float4(0.f, 0.f, 0.f, 0.f);
    for (int r = 0; r < 64; ++r) {
      float fv = f_lds[wv * 64 + r];
      float4 w = ((const float4*)W2)[(wv * 64 + r) * 64 + lane];
      acc.x += fv * w.x; acc.y += fv * w.y; acc.z += fv * w.z; acc.w += fv * w.w;
    }
    ((float4*)part)[wv * 64 + lane] = acc;
  }
  __syncthreads();
  {
    float sum = part[0 * 256 + tid] + part[1 * 256 + tid] + part[2 * 256 + tid] +
                part[3 * 256 + tid] + b2[tid];
    out[q * 256 + tid] += sum;
  }
}

// ============================ launch ============================
extern "C" void kernel_launch(void* const* d_in, const int* in_sizes, int n_in,
                              void* d_out, int out_size, void* d_ws, size_t ws_size,
                              hipStream_t stream) {
  const float* g      = (const float*)d_in[0];
  const float* s      = (const float*)d_in[1];
  const float* v      = (const float*)d_in[2];
  const float* geo_t  = (const float*)d_in[3];
  const float* surf_t = (const float*)d_in[4];
  const float* vol_t  = (const float*)d_in[5];
  const float* W1     = (const float*)d_in[6];
  const float* b1     = (const float*)d_in[7];
  const float* W2     = (const float*)d_in[8];
  const float* b2     = (const float*)d_in[9];
  float* out = (float*)d_out;

  const int NG = 4096, NS = 4096, NV = 8192;
  float* out_g = out;
  float* out_s = out + NG * 256;
  float* out_v = out + (NG + NS) * 256;

  const int stackid[7] = {0, 3, 4, 1, 5, 2, 6};
  const float* qp[7]   = {g, g, g, s, s, v, v};
  const int    nq[7]   = {NG, NG, NG, NS, NS, NV, NV};
  const int    pset[7] = {0, 1, 2, 1, 0, 2, 0};
  const float* praw[3] = {g, s, v};
  const int    setbase[3] = {0, 4096, 8192};

  const size_t FB = (size_t)36864 * 256 * sizeof(unsigned short);
  const size_t WT = (size_t)7 * 256 * 256 * sizeof(unsigned short);
  const size_t GI = (size_t)3 * 1024 * sizeof(int);
  const size_t need = FB + WT + GI + (size_t)16384 * sizeof(float4);

  if (ws_size >= need) {
    unsigned short* fbuf = (unsigned short*)d_ws;
    unsigned short* W2F  = (unsigned short*)((char*)d_ws + FB);
    int* starts = (int*)((char*)d_ws + FB + WT);
    float4* binned = (float4*)((char*)d_ws + FB + WT + GI);

    hipLaunchKernelGGL(prep_kernel, dim3(227), dim3(256), 0, stream,
                       g, s, v, W2, W2F, starts, binned);

    SelDesc sd;
    int blk = 0, frow = 0;
    int foffs[7];
    for (int i = 0; i < 7; ++i) {
      sd.qptr[i] = qp[i];
      sd.pptr[i] = praw[pset[i]];
      sd.pbase[i] = setbase[pset[i]];
      sd.soff[i] = pset[i] * 1024;
      sd.w1off[i] = stackid[i] * 768;
      sd.b1off[i] = stackid[i] * 256;
      sd.foff[i] = frow;
      foffs[i] = frow;
      sd.blkstart[i] = blk;
      blk += nq[i] / 4;
      frow += nq[i];
    }
    sd.blkstart[7] = blk;
    hipLaunchKernelGGL(bq_select_grid, dim3(blk), dim3(256), 0, stream,
                       sd, W1, b1, binned, starts, fbuf);

    GemmDesc gd;
    gd.basep[0] = geo_t;  gd.outp[0] = out_g;
    gd.basep[1] = surf_t; gd.outp[1] = out_s;
    gd.basep[2] = vol_t;  gd.outp[2] = out_v;
    gd.blkstart[0] = 0;
    gd.blkstart[1] = NG / 32;
    gd.blkstart[2] = NG / 32 + NS / 32;
    gd.blkstart[3] = NG / 32 + NS / 32 + NV / 32;
    gd.nst[0] = 3; gd.nst[1] = 2; gd.nst[2] = 2;
    const int ridx[3][3] = {{0, 1, 2}, {3, 4, -1}, {5, 6, -1}};
    for (int r = 0; r < 3; ++r)
      for (int t = 0; t < gd.nst[r]; ++t) {
        int i = ridx[r][t];
        gd.foff[r][t] = foffs[i];
        gd.w2off[r][t] = stackid[i] * 256 * 256;
        gd.b2off[r][t] = stackid[i] * 256;
      }
    hipLaunchKernelGGL(bq_gemm_mfma, dim3(gd.blkstart[3]), dim3(256), 0, stream,
                       gd, W2F, b2, fbuf);
  } else {
    const int total = (NG + NS + NV) * 256;
    hipLaunchKernelGGL(init_out_kernel, dim3(total / 256), dim3(256), 0, stream,
                       geo_t, surf_t, vol_t, out);
    auto launch = [&](int stack, const float* qp_, int Nq, const float* pp_, int Np, float* o) {
      hipLaunchKernelGGL(bq_stack_fused, dim3(Nq), dim3(256), 0, stream,
                         qp_, pp_, Np, W1 + stack * 768, b1 + stack * 256,
                         W2 + stack * 256 * 256, b2 + stack * 256, o);
    };
    launch(0, g, NG, g, NG, out_g);
    launch(3, g, NG, s, NS, out_g);
    launch(4, g, NG, v, NV, out_g);
    launch(1, s, NS, s, NS, out_s);
    launch(5, s, NS, g, NG, out_s);
    launch(2, v, NV, v, NV, out_v);
    launch(6, v, NV, g, NG, out_v);
  }
}